// Round 8
// baseline (384.492 us; speedup 1.0000x reference)
//
#include <hip/hip_runtime.h>

// Problem constants
#define NN   65536      // N nodes
#define NE   524288     // E edges
#define EPG  8192       // edges per graph

// Output float offsets in d_out (total 10111552 floats)
#define O1 7913472      // ei_new (2*E)
#define O2 8962048      // ea_new (E)
#define O3 9486336      // batch_out (30912)
#define O4 9517248      // perm (30912)
#define O5 9548160      // score_perm (30912)
#define O6 9579072      // sentence_scores (4096)
#define O7 9583168      // sentence_batch (4096)
#define O8 9587264      // keep (E)

// Scratch placement (float offsets), lifetime-verified (same as R5/R6):
#define CSR_OFF    8388608
#define DINV_OFF   9437184
#define Z_OFF      9502720
#define CNT_OFF    9568256
#define RSTART_OFF 9633792
#define CURSOR_OFF 9699344
#define WSUM_OFF   9764880
#define SCORE_OFF  65536
#define YLO_OFF    4194304   // ushort-plane offsets: yhi at float 0, ylo at float 4194304

typedef __attribute__((ext_vector_type(8))) short bfrag;
typedef __attribute__((ext_vector_type(4))) float f32x4;
typedef __attribute__((ext_vector_type(8))) unsigned short us8;

__device__ __forceinline__ unsigned monof(float f) {
  unsigned u = __float_as_uint(f);
  return (u & 0x80000000u) ? ~u : (u | 0x80000000u);  // ascending monotone map
}

__device__ __forceinline__ unsigned short bf16rne(float f) {
  unsigned u = __float_as_uint(f);
  return (unsigned short)((u + 0x7FFFu + ((u >> 16) & 1u)) >> 16);
}

__global__ void k_zero(unsigned* __restrict__ cnt, float* __restrict__ wsum,
                       float* __restrict__ z) {
  int n = blockIdx.x * 256 + threadIdx.x;
  if (n < NN) { cnt[n] = 0u; wsum[n] = 1.0f; z[n] = 0.0f; }
}

__global__ void k_hist(const int* __restrict__ ei, const float* __restrict__ w,
                       unsigned* __restrict__ cnt, float* __restrict__ wsum) {
  int e = blockIdx.x * 256 + threadIdx.x;
  if (e < NE) {
    int c = ei[NE + e];
    atomicAdd(&cnt[c], 1u);
    unsafeAtomicAdd(&wsum[c], w[e]);
  }
}

// Per graph: exclusive prefix over 1024 bins -> rstart/cursor; dinv = rsqrt(wsum).
__global__ __launch_bounds__(256) void k_prefix(const unsigned* __restrict__ cnt,
    const float* __restrict__ wsum, unsigned* __restrict__ rstart,
    unsigned* __restrict__ cursor, float* __restrict__ dinv) {
  __shared__ unsigned tmp[2][256];
  int g = blockIdx.x, t = threadIdx.x;
  int base = g << 10;
  unsigned c[4], sum = 0;
#pragma unroll
  for (int u = 0; u < 4; ++u) { c[u] = cnt[base + t * 4 + u]; sum += c[u]; }
  tmp[0][t] = sum;
  __syncthreads();
  int pin = 0;
  for (int off = 1; off < 256; off <<= 1) {
    int pout = pin ^ 1;
    unsigned v = tmp[pin][t];
    if (t >= off) v += tmp[pin][t - off];
    tmp[pout][t] = v;
    __syncthreads();
    pin = pout;
  }
  unsigned run = (t == 0) ? 0u : tmp[pin][t - 1];
#pragma unroll
  for (int u = 0; u < 4; ++u) {
    unsigned pos = (unsigned)(g << 13) + run;   // g*8192 + prefix
    rstart[base + t * 4 + u] = pos;
    cursor[base + t * 4 + u] = pos;
    run += c[u];
  }
#pragma unroll
  for (int u = 0; u < 4; ++u) {
    int n = base + t * 4 + u;
    dinv[n] = rsqrtf(wsum[n]);                   // wsum >= 1 always
  }
  if (g == 0 && t == 0) rstart[NN] = NE;
}

// Split+transpose W1 [256k][512c] fp32 -> w1hi/w1lo [512c][256k] bf16 (k-contiguous)
__global__ __launch_bounds__(256) void k_w1t(const float* __restrict__ W1,
    unsigned short* __restrict__ hi, unsigned short* __restrict__ lo) {
  __shared__ unsigned short sh[64][72], sl[64][72];
  int bk = blockIdx.x & 3, bc = blockIdx.x >> 2;
  int k0 = bk * 64, c0 = bc * 64;
  int t = threadIdx.x;
#pragma unroll
  for (int s = 0; s < 16; ++s) {
    int i = t + s * 256;
    int k = i >> 6, c = i & 63;
    float v = W1[(k0 + k) * 512 + c0 + c];
    unsigned short h = bf16rne(v);
    float hf = __uint_as_float((unsigned)h << 16);
    sh[c][k] = h;
    sl[c][k] = bf16rne(v - hf);
  }
  __syncthreads();
#pragma unroll
  for (int s = 0; s < 16; ++s) {
    int i = t + s * 256;
    int c = i >> 6, k = i & 63;
    hi[(c0 + c) * 256 + k0 + k] = sh[c][k];
    lo[(c0 + c) * 256 + k0 + k] = sl[c][k];
  }
}

// Scatter edges to dest-sorted CSR: csr[pos] = coef<<32 | dest_local<<16 | src_local
__global__ void k_scatter(const int* __restrict__ ei, const float* __restrict__ w,
                          const float* __restrict__ dinv, unsigned* __restrict__ cursor,
                          unsigned long long* __restrict__ csr) {
  int e = blockIdx.x * 256 + threadIdx.x;
  if (e < NE) {
    int r = ei[e], c = ei[NE + e];
    float cf = w[e] * dinv[r] * dinv[c];
    unsigned pos = atomicAdd(&cursor[c], 1u);
    csr[pos] = ((unsigned long long)__float_as_uint(cf) << 32) |
               ((unsigned)(c & 1023) << 16) | (unsigned)(r & 1023);
  }
}

// Aggregate x over normalized adjacency -> y bf16 hi/lo planes.
// Block = (graph g, 16-col chunk). 16-lane groups; each group runs TWO dest
// segments concurrently (d, d+32), batch-8 predicated, with NEXT-batch
// register prefetch so L2 latency hides under the 16-edge compute.
__global__ __launch_bounds__(256, 2) void k_aggx(const float* __restrict__ x,
    const unsigned long long* __restrict__ csr, const unsigned* __restrict__ rstart,
    const float* __restrict__ dinv, unsigned short* __restrict__ yhi,
    unsigned short* __restrict__ ylo, int gbase) {
  __shared__ float xs[1024 * 17];   // 68 KB
  __shared__ unsigned rp[1025];
  __shared__ float dv2[1024];
  int bid = blockIdx.x;
  int g  = bid & 31;                // graph g -> XCD g%8 (L2 locality)
  int cc = bid >> 5;                // 16 chunks of 16 columns
  int gg = gbase + g;
  int c0 = cc * 16;
  int t = threadIdx.x;
  int nbase = gg << 10;
  for (int i = t; i < 1024; i += 256) {
    rp[i] = rstart[nbase + i];
    float dv = dinv[nbase + i];
    dv2[i] = dv * dv;
  }
  if (t == 0) rp[1024] = rstart[nbase + 1024];
  // stage x[:, c0:c0+16] via float4 loads
#pragma unroll
  for (int s = 0; s < 16; ++s) {
    int i = t + s * 256;            // float4-slot: row = i>>2, quad = i&3
    int row = i >> 2, q = (i & 3) * 4;
    float4 v = *(const float4*)&x[(nbase + row) * 256 + c0 + q];
    float* d = &xs[row * 17 + q];
    d[0] = v.x; d[1] = v.y; d[2] = v.z; d[3] = v.w;
  }
  __syncthreads();
  int j = t & 15, grp = t >> 4;     // 16 groups of 16 lanes; lane j = column
  int dbase = grp * 64;             // group owns dests [dbase, dbase+64)
  for (int dd = 0; dd < 32; ++dd) {
    int d0 = dbase + dd, d1 = d0 + 32;
    unsigned p0 = rp[d0], q0 = rp[d0 + 1];
    unsigned p1 = rp[d1], q1 = rp[d1 + 1];
    int L0 = (int)(q0 - p0), L1 = (int)(q1 - p1);
    int L = L0 > L1 ? L0 : L1;
    int M0 = L0 > 0 ? L0 - 1 : 0;   // clamp limits
    int M1 = L1 > 0 ? L1 - 1 : 0;
    float a0 = dv2[d0] * xs[d0 * 17 + j];
    float a1 = dv2[d1] * xs[d1 * 17 + j];
    if (L > 0) {
      unsigned long long cb0[8], cb1[8], nb0[8], nb1[8];
#pragma unroll
      for (int u = 0; u < 8; ++u) {           // preload batch 0 (clamped)
        cb0[u] = csr[p0 + (u < M0 ? u : M0)];
        cb1[u] = csr[p1 + (u < M1 ? u : M1)];
      }
      for (int k = 0; k < L; k += 8) {
        int kn = k + 8;
#pragma unroll
        for (int u = 0; u < 8; ++u) {         // prefetch next batch
          int i0 = kn + u; i0 = i0 < M0 ? i0 : M0;
          int i1 = kn + u; i1 = i1 < M1 ? i1 : M1;
          nb0[u] = csr[p0 + i0];
          nb1[u] = csr[p1 + i1];
        }
#pragma unroll
        for (int u = 0; u < 8; ++u) {         // compute current batch
          int kk = k + u;
          float f0 = kk < L0 ? __uint_as_float((unsigned)(cb0[u] >> 32)) : 0.0f;
          float f1 = kk < L1 ? __uint_as_float((unsigned)(cb1[u] >> 32)) : 0.0f;
          a0 += f0 * xs[(unsigned)(cb0[u] & 1023) * 17 + j];
          a1 += f1 * xs[(unsigned)(cb1[u] & 1023) * 17 + j];
        }
#pragma unroll
        for (int u = 0; u < 8; ++u) { cb0[u] = nb0[u]; cb1[u] = nb1[u]; }
      }
    }
    int i0 = ((g << 10) + d0) * 256 + c0 + j;
    int i1 = ((g << 10) + d1) * 256 + c0 + j;
    unsigned short h0 = bf16rne(a0), h1 = bf16rne(a1);
    yhi[i0] = h0;
    ylo[i0] = bf16rne(a0 - __uint_as_float((unsigned)h0 << 16));
    yhi[i1] = h1;
    ylo[i1] = bf16rne(a1 - __uint_as_float((unsigned)h1 << 16));
  }
}

// MFMA GEMM: h = y(32768x256) @ W1(256x512) via bf16 hi/lo 3-product split,
// fused +b1 -> LeakyReLU -> dot W2 -> atomic z.  128x128 tile, 4 waves (64x64).
__global__ __launch_bounds__(256, 2) void k_gemm(
    const unsigned short* __restrict__ yhi, const unsigned short* __restrict__ ylo,
    const unsigned short* __restrict__ w1hi, const unsigned short* __restrict__ w1lo,
    const float* __restrict__ b1, const float* __restrict__ W2,
    float* __restrict__ z, int node_base) {
  __shared__ unsigned short Ah_s[128 * 40], Al_s[128 * 40];  // [row][40] ushort, 80B stride
  __shared__ unsigned short Bh_s[128 * 40], Bl_s[128 * 40];  // [col][40]
  int bx = blockIdx.x & 3, by = blockIdx.x >> 2;
  int r0 = by * 128, c0 = bx * 128;
  int t = threadIdx.x;
  int lane = t & 63, wid = t >> 6;
  int wr = wid >> 1, wc = wid & 1;         // wave tile origin (wr*64, wc*64)
  int lr = lane & 15, hg = lane >> 4;
  f32x4 acc[4][4];
#pragma unroll
  for (int m = 0; m < 4; ++m)
#pragma unroll
    for (int n = 0; n < 4; ++n)
      acc[m][n] = (f32x4){0.0f, 0.0f, 0.0f, 0.0f};
  int rr = t >> 2, kq = (t & 3) * 8;       // staging: rows rr, rr+64; 8-elem k-chunk
  for (int kt = 0; kt < 256; kt += 32) {
    us8 va0 = *(const us8*)&yhi[(r0 + rr) * 256 + kt + kq];
    us8 va1 = *(const us8*)&yhi[(r0 + rr + 64) * 256 + kt + kq];
    us8 vb0 = *(const us8*)&ylo[(r0 + rr) * 256 + kt + kq];
    us8 vb1 = *(const us8*)&ylo[(r0 + rr + 64) * 256 + kt + kq];
    us8 vc0 = *(const us8*)&w1hi[(c0 + rr) * 256 + kt + kq];
    us8 vc1 = *(const us8*)&w1hi[(c0 + rr + 64) * 256 + kt + kq];
    us8 vd0 = *(const us8*)&w1lo[(c0 + rr) * 256 + kt + kq];
    us8 vd1 = *(const us8*)&w1lo[(c0 + rr + 64) * 256 + kt + kq];
    __syncthreads();                        // prev-step frag reads complete
    *(us8*)&Ah_s[rr * 40 + kq] = va0;  *(us8*)&Ah_s[(rr + 64) * 40 + kq] = va1;
    *(us8*)&Al_s[rr * 40 + kq] = vb0;  *(us8*)&Al_s[(rr + 64) * 40 + kq] = vb1;
    *(us8*)&Bh_s[rr * 40 + kq] = vc0;  *(us8*)&Bh_s[(rr + 64) * 40 + kq] = vc1;
    *(us8*)&Bl_s[rr * 40 + kq] = vd0;  *(us8*)&Bl_s[(rr + 64) * 40 + kq] = vd1;
    __syncthreads();
    bfrag Ah[4], Al[4], Bh[4], Bl[4];
#pragma unroll
    for (int m = 0; m < 4; ++m) {
      int ra = (wr * 64 + m * 16 + lr) * 40 + hg * 8;
      Ah[m] = *(const bfrag*)&Ah_s[ra];
      Al[m] = *(const bfrag*)&Al_s[ra];
      int rb = (wc * 64 + m * 16 + lr) * 40 + hg * 8;
      Bh[m] = *(const bfrag*)&Bh_s[rb];
      Bl[m] = *(const bfrag*)&Bl_s[rb];
    }
#pragma unroll
    for (int m = 0; m < 4; ++m)
#pragma unroll
      for (int n = 0; n < 4; ++n) {
        acc[m][n] = __builtin_amdgcn_mfma_f32_16x16x32_bf16(Ah[m], Bh[n], acc[m][n], 0, 0, 0);
        acc[m][n] = __builtin_amdgcn_mfma_f32_16x16x32_bf16(Ah[m], Bl[n], acc[m][n], 0, 0, 0);
        acc[m][n] = __builtin_amdgcn_mfma_f32_16x16x32_bf16(Al[m], Bh[n], acc[m][n], 0, 0, 0);
      }
  }
  // epilogue: +b1, LeakyReLU, dot W2, reduce over the 16 col-lanes, atomic z
  float p[4][4];
#pragma unroll
  for (int m = 0; m < 4; ++m)
#pragma unroll
    for (int i = 0; i < 4; ++i) p[m][i] = 0.0f;
#pragma unroll
  for (int n = 0; n < 4; ++n) {
    int col = c0 + wc * 64 + n * 16 + lr;
    float b1v = b1[col], w2v = W2[col];
#pragma unroll
    for (int m = 0; m < 4; ++m)
#pragma unroll
      for (int i = 0; i < 4; ++i) {
        float v = acc[m][n][i] + b1v;
        v = v > 0.0f ? v : 0.01f * v;
        p[m][i] += v * w2v;
      }
  }
#pragma unroll
  for (int off = 8; off > 0; off >>= 1)
#pragma unroll
    for (int m = 0; m < 4; ++m)
#pragma unroll
      for (int i = 0; i < 4; ++i)
        p[m][i] += __shfl_xor(p[m][i], off, 16);
  if (lr == 0) {
    int rbase = node_base + r0 + wr * 64 + hg * 4;
#pragma unroll
    for (int m = 0; m < 4; ++m)
#pragma unroll
      for (int i = 0; i < 4; ++i)
        unsafeAtomicAdd(&z[rbase + m * 16 + i], p[m][i]);
  }
}

// score[n] = b2 + dinv[n]^2*z[n] + sum_{e in seg(n)} coef[e]*z[global_row]
// Also initializes mask[n] = -1 (fused, saves a launch).
__global__ void k_score(const unsigned long long* __restrict__ csr,
                        const unsigned* __restrict__ rstart,
                        const float* __restrict__ dinv, const float* __restrict__ z,
                        const float* __restrict__ b2, float* __restrict__ score,
                        int* __restrict__ mask) {
  int n = blockIdx.x * 256 + threadIdx.x;
  if (n >= NN) return;
  mask[n] = -1;
  int nb = n & ~1023;
  float dv = dinv[n];
  float a = b2[0] + dv * dv * z[n];
  unsigned s = rstart[n], epos = rstart[n + 1];
  for (unsigned e = s; e < epos; ++e) {
    unsigned long long p = csr[e];
    a += __uint_as_float((unsigned)(p >> 32)) * z[nb + (unsigned)(p & 1023)];
  }
  score[n] = a;
}

__device__ void bitonic(unsigned long long* keys, int n, int t, int nt) {
  for (int k = 2; k <= n; k <<= 1)
    for (int jj = k >> 1; jj > 0; jj >>= 1) {
      __syncthreads();
      for (int i = t; i < n; i += nt) {
        int ixj = i ^ jj;
        if (ixj > i) {
          unsigned long long a = keys[i], c = keys[ixj];
          bool up = ((i & k) == 0);
          if ((a > c) == up) { keys[i] = c; keys[ixj] = a; }
        }
      }
    }
  __syncthreads();
}

__global__ __launch_bounds__(256) void k_topk(const float* __restrict__ score,
                                              int* __restrict__ mask,
                                              float* __restrict__ out) {
  __shared__ unsigned long long keys[1024];
  int b = blockIdx.x, t = threadIdx.x;
  int base = b << 10;
  if (t < 64) {
    float v = score[base + t];
    keys[t] = ((unsigned long long)(~monof(v)) << 32) | (unsigned)t;
    out[O6 + b * 64 + t] = v;
    out[O7 + b * 64 + t] = (float)b;
  }
  __syncthreads();
  bitonic(keys, 64, t, 256);
  if (t < 3) {
    int idx = (int)(keys[t] & 0xFFFFFFFFull);
    int node = base + idx;
    int pos = b * 3 + t;
    mask[node] = pos;
    out[O4 + pos] = (float)node;
    out[O5 + pos] = score[node];
    out[O3 + pos] = (float)b;
  }
  __syncthreads();
  for (int i = t; i < 1024; i += 256) {
    if (i < 960) {
      float v = score[base + 64 + i];
      keys[i] = ((unsigned long long)(~monof(v)) << 32) | (unsigned)i;
    } else {
      keys[i] = 0xFFFFFFFFFFFFFFFFull;
    }
  }
  __syncthreads();
  bitonic(keys, 1024, t, 256);
  for (int r = t; r < 480; r += 256) {
    int idx = (int)(keys[r] & 0xFFFFFFFFull);
    int node = base + 64 + idx;
    int pos = 192 + b * 480 + r;
    mask[node] = pos;
    out[O4 + pos] = (float)node;
    out[O5 + pos] = score[node];
    out[O3 + pos] = (float)b;
  }
}

__global__ void k_edges(const int* __restrict__ ei, const float* __restrict__ w,
                        const int* __restrict__ mask, float* __restrict__ out) {
  int e = blockIdx.x * 256 + threadIdx.x;
  if (e >= NE) return;
  int nr = mask[ei[e]];
  int nc = mask[ei[NE + e]];
  bool keep = (nr >= 0) && (nc >= 0);
  out[O1 + e]      = keep ? (float)nr : -1.0f;
  out[O1 + NE + e] = keep ? (float)nc : -1.0f;
  out[O2 + e]      = keep ? w[e] : 0.0f;
  out[O8 + e]      = keep ? 1.0f : 0.0f;
}

__global__ void k_xout(const float* __restrict__ x, const float* __restrict__ permF,
                       const float* __restrict__ scoreP, float* __restrict__ out) {
  int i = blockIdx.x;
  int node = (int)permF[i];
  float s = scoreP[i];
  const float4* xr = (const float4*)&x[node * 256];
  float4* o = (float4*)&out[i * 256];
  float4 v = xr[threadIdx.x];
  o[threadIdx.x] = make_float4(v.x * s, v.y * s, v.z * s, v.w * s);
}

extern "C" void kernel_launch(void* const* d_in, const int* in_sizes, int n_in,
                              void* d_out, int out_size, void* d_ws, size_t ws_size,
                              hipStream_t stream) {
  (void)in_sizes; (void)n_in; (void)out_size; (void)d_ws; (void)ws_size;
  const float* x  = (const float*)d_in[0];
  const int*   ei = (const int*)d_in[1];
  const float* w  = (const float*)d_in[2];
  const float* W1 = (const float*)d_in[4];
  const float* b1 = (const float*)d_in[5];
  const float* W2 = (const float*)d_in[6];
  const float* b2 = (const float*)d_in[7];
  float* out    = (float*)d_out;
  unsigned short* yhi = (unsigned short*)out;                  // [32768*256] per chunk
  unsigned short* ylo = (unsigned short*)(out + YLO_OFF);
  unsigned long long* csr = (unsigned long long*)(out + CSR_OFF);
  float* dinv   = out + DINV_OFF;
  float* z      = out + Z_OFF;
  unsigned* cnt    = (unsigned*)(out + CNT_OFF);
  unsigned* rstart = (unsigned*)(out + RSTART_OFF);
  unsigned* cursor = (unsigned*)(out + CURSOR_OFF);
  float* wsum   = out + WSUM_OFF;
  unsigned short* w1hi = (unsigned short*)(out + CNT_OFF);     // reuse cnt after k_prefix
  unsigned short* w1lo = (unsigned short*)(out + WSUM_OFF);    // reuse wsum after k_prefix
  float* score  = out + SCORE_OFF;
  int*   mask   = (int*)d_out;

  k_zero<<<256, 256, 0, stream>>>(cnt, wsum, z);
  k_hist<<<2048, 256, 0, stream>>>(ei, w, cnt, wsum);
  k_prefix<<<64, 256, 0, stream>>>(cnt, wsum, rstart, cursor, dinv);
  k_w1t<<<32, 256, 0, stream>>>(W1, w1hi, w1lo);               // cnt/wsum dead now
  k_scatter<<<2048, 256, 0, stream>>>(ei, w, dinv, cursor, csr);
  for (int ch = 0; ch < 2; ++ch) {
    k_aggx<<<512, 256, 0, stream>>>(x, csr, rstart, dinv, yhi, ylo, ch * 32);
    k_gemm<<<1024, 256, 0, stream>>>(yhi, ylo, w1hi, w1lo, b1, W2, z, ch * 32768);
  }
  k_score<<<256, 256, 0, stream>>>(csr, rstart, dinv, z, b2, score, mask);
  k_topk<<<64, 256, 0, stream>>>(score, mask, out);
  k_edges<<<2048, 256, 0, stream>>>(ei, w, mask, out);
  k_xout<<<30912, 64, 0, stream>>>(x, out + O4, out + O5, out);
}

// Round 9
// 318.418 us; speedup vs baseline: 1.2075x; 1.2075x over previous
//
#include <hip/hip_runtime.h>

// Problem constants
#define NN   65536      // N nodes
#define NE   524288     // E edges
#define EPG  8192       // edges per graph

// Output float offsets in d_out (total 10111552 floats)
#define O1 7913472      // ei_new (2*E)
#define O2 8962048      // ea_new (E)
#define O3 9486336      // batch_out (30912)
#define O4 9517248      // perm (30912)
#define O5 9548160      // score_perm (30912)
#define O6 9579072      // sentence_scores (4096)
#define O7 9583168      // sentence_batch (4096)
#define O8 9587264      // keep (E)

// Scratch placement (float offsets), lifetime-verified:
//  yhi/ylo [0, 8388608)        die after last k_gemm
//  csr    [8388608, 9437184)   u64; dies after k_score (before k_edges O1/O2)
//  dinv   [9437184, 9502720)   dies after k_score
//  z      [9502720, 9568256)   dies after k_score (k_topk writes O4/O5 later)
//  w1hi   [9568256, 9633792)   dies after last k_gemm (before k_edges O8)
//  rstart [9633792, 9699329)   u32[65537]; dies after k_score
//  cursor [9699344, 9764880)   dies after k_scatter
//  w1lo   [9764880, 9830416)   dies after last k_gemm
//  hist64 [9830416, 9961488)   u64[65536]; dies after k_prefix (k_edges writes O8 last)
//  score  [65536, 131072)      written after y planes die; dies after k_topk
//  mask   ints [0, 65536)      written after GEMMs; read k_edges; k_xout overwrites last
#define CSR_OFF    8388608
#define DINV_OFF   9437184
#define Z_OFF      9502720
#define W1HI_OFF   9568256
#define RSTART_OFF 9633792
#define CURSOR_OFF 9699344
#define W1LO_OFF   9764880
#define HIST_OFF   9830416
#define SCORE_OFF  65536
#define YLO_OFF    4194304   // ushort-plane offsets: yhi at float 0, ylo at float 4194304

typedef __attribute__((ext_vector_type(8))) short bfrag;
typedef __attribute__((ext_vector_type(4))) float f32x4;
typedef __attribute__((ext_vector_type(8))) unsigned short us8;

__device__ __forceinline__ unsigned monof(float f) {
  unsigned u = __float_as_uint(f);
  return (u & 0x80000000u) ? ~u : (u | 0x80000000u);  // ascending monotone map
}

__device__ __forceinline__ unsigned short bf16rne(float f) {
  unsigned u = __float_as_uint(f);
  return (unsigned short)((u + 0x7FFFu + ((u >> 16) & 1u)) >> 16);
}

__global__ void k_zero(unsigned long long* __restrict__ hist, float* __restrict__ z) {
  int n = blockIdx.x * 256 + threadIdx.x;
  if (n < NN) { hist[n] = 0ull; z[n] = 0.0f; }
}

// One packed u64 atomic per edge: count in bits>=40, wsum fixed-point 2^-20 below.
__global__ void k_hist(const int* __restrict__ ei, const float* __restrict__ w,
                       unsigned long long* __restrict__ hist) {
  int e = blockIdx.x * 256 + threadIdx.x;
  if (e < NE) {
    int c = ei[NE + e];
    unsigned long long add = (1ull << 40) |
        (unsigned long long)(unsigned)__float2uint_rn(w[e] * 1048576.0f);
    atomicAdd(&hist[c], add);
  }
}

// Per graph: exclusive prefix over 1024 bins -> rstart/cursor; dinv from fixed-point wsum.
__global__ __launch_bounds__(256) void k_prefix(const unsigned long long* __restrict__ hist,
    unsigned* __restrict__ rstart, unsigned* __restrict__ cursor, float* __restrict__ dinv) {
  __shared__ unsigned tmp[2][256];
  int g = blockIdx.x, t = threadIdx.x;
  int base = g << 10;
  unsigned c[4], sum = 0;
  unsigned long long hv[4];
#pragma unroll
  for (int u = 0; u < 4; ++u) {
    hv[u] = hist[base + t * 4 + u];
    c[u] = (unsigned)(hv[u] >> 40);
    sum += c[u];
  }
  tmp[0][t] = sum;
  __syncthreads();
  int pin = 0;
  for (int off = 1; off < 256; off <<= 1) {
    int pout = pin ^ 1;
    unsigned v = tmp[pin][t];
    if (t >= off) v += tmp[pin][t - off];
    tmp[pout][t] = v;
    __syncthreads();
    pin = pout;
  }
  unsigned run = (t == 0) ? 0u : tmp[pin][t - 1];
#pragma unroll
  for (int u = 0; u < 4; ++u) {
    unsigned pos = (unsigned)(g << 13) + run;   // g*8192 + prefix
    rstart[base + t * 4 + u] = pos;
    cursor[base + t * 4 + u] = pos;
    run += c[u];
  }
#pragma unroll
  for (int u = 0; u < 4; ++u) {
    int n = base + t * 4 + u;
    float wsum = 1.0f + (float)(hv[u] & ((1ull << 40) - 1)) * 9.5367431640625e-07f;
    dinv[n] = rsqrtf(wsum);
  }
  if (g == 0 && t == 0) rstart[NN] = NE;
}

// Split+transpose W1 [256k][512c] fp32 -> w1hi/w1lo [512c][256k] bf16 (k-contiguous)
__global__ __launch_bounds__(256) void k_w1t(const float* __restrict__ W1,
    unsigned short* __restrict__ hi, unsigned short* __restrict__ lo) {
  __shared__ unsigned short sh[64][72], sl[64][72];
  int bk = blockIdx.x & 3, bc = blockIdx.x >> 2;
  int k0 = bk * 64, c0 = bc * 64;
  int t = threadIdx.x;
#pragma unroll
  for (int s = 0; s < 16; ++s) {
    int i = t + s * 256;
    int k = i >> 6, c = i & 63;
    float v = W1[(k0 + k) * 512 + c0 + c];
    unsigned short h = bf16rne(v);
    float hf = __uint_as_float((unsigned)h << 16);
    sh[c][k] = h;
    sl[c][k] = bf16rne(v - hf);
  }
  __syncthreads();
#pragma unroll
  for (int s = 0; s < 16; ++s) {
    int i = t + s * 256;
    int c = i >> 6, k = i & 63;
    hi[(c0 + c) * 256 + k0 + k] = sh[c][k];
    lo[(c0 + c) * 256 + k0 + k] = sl[c][k];
  }
}

// Scatter edges to dest-sorted CSR: csr[pos] = coef<<32 | dest_local<<16 | src_local
__global__ void k_scatter(const int* __restrict__ ei, const float* __restrict__ w,
                          const float* __restrict__ dinv, unsigned* __restrict__ cursor,
                          unsigned long long* __restrict__ csr) {
  int e = blockIdx.x * 256 + threadIdx.x;
  if (e < NE) {
    int r = ei[e], c = ei[NE + e];
    float cf = w[e] * dinv[r] * dinv[c];
    unsigned pos = atomicAdd(&cursor[c], 1u);
    csr[pos] = ((unsigned long long)__float_as_uint(cf) << 32) |
               ((unsigned)(c & 1023) << 16) | (unsigned)(r & 1023);
  }
}

// Aggregate x over normalized adjacency -> y bf16 hi/lo planes.
// Block = (graph g, 16-col chunk). 16-lane groups; each group runs TWO dest
// segments concurrently (d, d+32), batch-8 predicated (16 independent loads
// in flight per iteration), single-buffer so codegen stays register-resident.
__global__ __launch_bounds__(256, 2) void k_aggx(const float* __restrict__ x,
    const unsigned long long* __restrict__ csr, const unsigned* __restrict__ rstart,
    const float* __restrict__ dinv, unsigned short* __restrict__ yhi,
    unsigned short* __restrict__ ylo, int gbase) {
  __shared__ float xs[1024 * 17];   // 68 KB
  __shared__ unsigned rp[1025];
  __shared__ float dv2[1024];
  int bid = blockIdx.x;
  int g  = bid & 31;                // graph g -> XCD g%8 (L2 locality)
  int cc = bid >> 5;                // 16 chunks of 16 columns
  int gg = gbase + g;
  int c0 = cc * 16;
  int t = threadIdx.x;
  int nbase = gg << 10;
  for (int i = t; i < 1024; i += 256) {
    rp[i] = rstart[nbase + i];
    float dv = dinv[nbase + i];
    dv2[i] = dv * dv;
  }
  if (t == 0) rp[1024] = rstart[nbase + 1024];
  // stage x[:, c0:c0+16] via float4 loads
#pragma unroll
  for (int s = 0; s < 16; ++s) {
    int i = t + s * 256;            // float4-slot: row = i>>2, quad = i&3
    int row = i >> 2, q = (i & 3) * 4;
    float4 v = *(const float4*)&x[(nbase + row) * 256 + c0 + q];
    float* d = &xs[row * 17 + q];
    d[0] = v.x; d[1] = v.y; d[2] = v.z; d[3] = v.w;
  }
  __syncthreads();
  int j = t & 15, grp = t >> 4;     // 16 groups of 16 lanes; lane j = column
  int dbase = grp * 64;             // group owns dests [dbase, dbase+64)
  for (int dd = 0; dd < 32; ++dd) {
    int d0 = dbase + dd, d1 = d0 + 32;
    unsigned p0 = rp[d0], q0 = rp[d0 + 1];
    unsigned p1 = rp[d1], q1 = rp[d1 + 1];
    int L0 = (int)(q0 - p0), L1 = (int)(q1 - p1);
    int L = L0 > L1 ? L0 : L1;
    int M0 = L0 > 0 ? L0 - 1 : 0;   // clamp limits
    int M1 = L1 > 0 ? L1 - 1 : 0;
    float a0 = dv2[d0] * xs[d0 * 17 + j];
    float a1 = dv2[d1] * xs[d1 * 17 + j];
    for (int k = 0; k < L; k += 8) {
      unsigned long long cb0[8], cb1[8];
#pragma unroll
      for (int u = 0; u < 8; ++u) {         // 16 independent loads in flight
        int i0 = k + u; i0 = i0 < M0 ? i0 : M0;
        int i1 = k + u; i1 = i1 < M1 ? i1 : M1;
        cb0[u] = csr[p0 + i0];
        cb1[u] = csr[p1 + i1];
      }
#pragma unroll
      for (int u = 0; u < 8; ++u) {
        int kk = k + u;
        float f0 = kk < L0 ? __uint_as_float((unsigned)(cb0[u] >> 32)) : 0.0f;
        float f1 = kk < L1 ? __uint_as_float((unsigned)(cb1[u] >> 32)) : 0.0f;
        a0 += f0 * xs[(unsigned)(cb0[u] & 1023) * 17 + j];
        a1 += f1 * xs[(unsigned)(cb1[u] & 1023) * 17 + j];
      }
    }
    int i0 = ((g << 10) + d0) * 256 + c0 + j;
    int i1 = ((g << 10) + d1) * 256 + c0 + j;
    unsigned short h0 = bf16rne(a0), h1 = bf16rne(a1);
    yhi[i0] = h0;
    ylo[i0] = bf16rne(a0 - __uint_as_float((unsigned)h0 << 16));
    yhi[i1] = h1;
    ylo[i1] = bf16rne(a1 - __uint_as_float((unsigned)h1 << 16));
  }
}

// MFMA GEMM: h = y(32768x256) @ W1(256x512) via bf16 hi/lo 3-product split,
// fused +b1 -> LeakyReLU -> dot W2 -> atomic z.  128x128 tile, 4 waves (64x64).
__global__ __launch_bounds__(256, 2) void k_gemm(
    const unsigned short* __restrict__ yhi, const unsigned short* __restrict__ ylo,
    const unsigned short* __restrict__ w1hi, const unsigned short* __restrict__ w1lo,
    const float* __restrict__ b1, const float* __restrict__ W2,
    float* __restrict__ z, int node_base) {
  __shared__ unsigned short Ah_s[128 * 40], Al_s[128 * 40];  // [row][40] ushort, 80B stride
  __shared__ unsigned short Bh_s[128 * 40], Bl_s[128 * 40];  // [col][40]
  int bx = blockIdx.x & 3, by = blockIdx.x >> 2;
  int r0 = by * 128, c0 = bx * 128;
  int t = threadIdx.x;
  int lane = t & 63, wid = t >> 6;
  int wr = wid >> 1, wc = wid & 1;         // wave tile origin (wr*64, wc*64)
  int lr = lane & 15, hg = lane >> 4;
  f32x4 acc[4][4];
#pragma unroll
  for (int m = 0; m < 4; ++m)
#pragma unroll
    for (int n = 0; n < 4; ++n)
      acc[m][n] = (f32x4){0.0f, 0.0f, 0.0f, 0.0f};
  int rr = t >> 2, kq = (t & 3) * 8;       // staging: rows rr, rr+64; 8-elem k-chunk
  for (int kt = 0; kt < 256; kt += 32) {
    us8 va0 = *(const us8*)&yhi[(r0 + rr) * 256 + kt + kq];
    us8 va1 = *(const us8*)&yhi[(r0 + rr + 64) * 256 + kt + kq];
    us8 vb0 = *(const us8*)&ylo[(r0 + rr) * 256 + kt + kq];
    us8 vb1 = *(const us8*)&ylo[(r0 + rr + 64) * 256 + kt + kq];
    us8 vc0 = *(const us8*)&w1hi[(c0 + rr) * 256 + kt + kq];
    us8 vc1 = *(const us8*)&w1hi[(c0 + rr + 64) * 256 + kt + kq];
    us8 vd0 = *(const us8*)&w1lo[(c0 + rr) * 256 + kt + kq];
    us8 vd1 = *(const us8*)&w1lo[(c0 + rr + 64) * 256 + kt + kq];
    __syncthreads();                        // prev-step frag reads complete
    *(us8*)&Ah_s[rr * 40 + kq] = va0;  *(us8*)&Ah_s[(rr + 64) * 40 + kq] = va1;
    *(us8*)&Al_s[rr * 40 + kq] = vb0;  *(us8*)&Al_s[(rr + 64) * 40 + kq] = vb1;
    *(us8*)&Bh_s[rr * 40 + kq] = vc0;  *(us8*)&Bh_s[(rr + 64) * 40 + kq] = vc1;
    *(us8*)&Bl_s[rr * 40 + kq] = vd0;  *(us8*)&Bl_s[(rr + 64) * 40 + kq] = vd1;
    __syncthreads();
    bfrag Ah[4], Al[4], Bh[4], Bl[4];
#pragma unroll
    for (int m = 0; m < 4; ++m) {
      int ra = (wr * 64 + m * 16 + lr) * 40 + hg * 8;
      Ah[m] = *(const bfrag*)&Ah_s[ra];
      Al[m] = *(const bfrag*)&Al_s[ra];
      int rb = (wc * 64 + m * 16 + lr) * 40 + hg * 8;
      Bh[m] = *(const bfrag*)&Bh_s[rb];
      Bl[m] = *(const bfrag*)&Bl_s[rb];
    }
#pragma unroll
    for (int m = 0; m < 4; ++m)
#pragma unroll
      for (int n = 0; n < 4; ++n) {
        acc[m][n] = __builtin_amdgcn_mfma_f32_16x16x32_bf16(Ah[m], Bh[n], acc[m][n], 0, 0, 0);
        acc[m][n] = __builtin_amdgcn_mfma_f32_16x16x32_bf16(Ah[m], Bl[n], acc[m][n], 0, 0, 0);
        acc[m][n] = __builtin_amdgcn_mfma_f32_16x16x32_bf16(Al[m], Bh[n], acc[m][n], 0, 0, 0);
      }
  }
  // epilogue: +b1, LeakyReLU, dot W2, reduce over the 16 col-lanes, atomic z
  float p[4][4];
#pragma unroll
  for (int m = 0; m < 4; ++m)
#pragma unroll
    for (int i = 0; i < 4; ++i) p[m][i] = 0.0f;
#pragma unroll
  for (int n = 0; n < 4; ++n) {
    int col = c0 + wc * 64 + n * 16 + lr;
    float b1v = b1[col], w2v = W2[col];
#pragma unroll
    for (int m = 0; m < 4; ++m)
#pragma unroll
      for (int i = 0; i < 4; ++i) {
        float v = acc[m][n][i] + b1v;
        v = v > 0.0f ? v : 0.01f * v;
        p[m][i] += v * w2v;
      }
  }
#pragma unroll
  for (int off = 8; off > 0; off >>= 1)
#pragma unroll
    for (int m = 0; m < 4; ++m)
#pragma unroll
      for (int i = 0; i < 4; ++i)
        p[m][i] += __shfl_xor(p[m][i], off, 16);
  if (lr == 0) {
    int rbase = node_base + r0 + wr * 64 + hg * 4;
#pragma unroll
    for (int m = 0; m < 4; ++m)
#pragma unroll
      for (int i = 0; i < 4; ++i)
        unsafeAtomicAdd(&z[rbase + m * 16 + i], p[m][i]);
  }
}

// score[n] = b2 + dinv[n]^2*z[n] + sum_{e in seg(n)} coef[e]*z[global_row]
// Also initializes mask[n] = -1 (fused, saves a launch).
__global__ void k_score(const unsigned long long* __restrict__ csr,
                        const unsigned* __restrict__ rstart,
                        const float* __restrict__ dinv, const float* __restrict__ z,
                        const float* __restrict__ b2, float* __restrict__ score,
                        int* __restrict__ mask) {
  int n = blockIdx.x * 256 + threadIdx.x;
  if (n >= NN) return;
  mask[n] = -1;
  int nb = n & ~1023;
  float dv = dinv[n];
  float a = b2[0] + dv * dv * z[n];
  unsigned s = rstart[n], epos = rstart[n + 1];
  for (unsigned e = s; e < epos; ++e) {
    unsigned long long p = csr[e];
    a += __uint_as_float((unsigned)(p >> 32)) * z[nb + (unsigned)(p & 1023)];
  }
  score[n] = a;
}

__device__ void bitonic(unsigned long long* keys, int n, int t, int nt) {
  for (int k = 2; k <= n; k <<= 1)
    for (int jj = k >> 1; jj > 0; jj >>= 1) {
      __syncthreads();
      for (int i = t; i < n; i += nt) {
        int ixj = i ^ jj;
        if (ixj > i) {
          unsigned long long a = keys[i], c = keys[ixj];
          bool up = ((i & k) == 0);
          if ((a > c) == up) { keys[i] = c; keys[ixj] = a; }
        }
      }
    }
  __syncthreads();
}

__global__ __launch_bounds__(256) void k_topk(const float* __restrict__ score,
                                              int* __restrict__ mask,
                                              float* __restrict__ out) {
  __shared__ unsigned long long keys[1024];
  int b = blockIdx.x, t = threadIdx.x;
  int base = b << 10;
  if (t < 64) {
    float v = score[base + t];
    keys[t] = ((unsigned long long)(~monof(v)) << 32) | (unsigned)t;
    out[O6 + b * 64 + t] = v;
    out[O7 + b * 64 + t] = (float)b;
  }
  __syncthreads();
  bitonic(keys, 64, t, 256);
  if (t < 3) {
    int idx = (int)(keys[t] & 0xFFFFFFFFull);
    int node = base + idx;
    int pos = b * 3 + t;
    mask[node] = pos;
    out[O4 + pos] = (float)node;
    out[O5 + pos] = score[node];
    out[O3 + pos] = (float)b;
  }
  __syncthreads();
  for (int i = t; i < 1024; i += 256) {
    if (i < 960) {
      float v = score[base + 64 + i];
      keys[i] = ((unsigned long long)(~monof(v)) << 32) | (unsigned)i;
    } else {
      keys[i] = 0xFFFFFFFFFFFFFFFFull;
    }
  }
  __syncthreads();
  bitonic(keys, 1024, t, 256);
  for (int r = t; r < 480; r += 256) {
    int idx = (int)(keys[r] & 0xFFFFFFFFull);
    int node = base + 64 + idx;
    int pos = 192 + b * 480 + r;
    mask[node] = pos;
    out[O4 + pos] = (float)node;
    out[O5 + pos] = score[node];
    out[O3 + pos] = (float)b;
  }
}

__global__ void k_edges(const int* __restrict__ ei, const float* __restrict__ w,
                        const int* __restrict__ mask, float* __restrict__ out) {
  int e = blockIdx.x * 256 + threadIdx.x;
  if (e >= NE) return;
  int nr = mask[ei[e]];
  int nc = mask[ei[NE + e]];
  bool keep = (nr >= 0) && (nc >= 0);
  out[O1 + e]      = keep ? (float)nr : -1.0f;
  out[O1 + NE + e] = keep ? (float)nc : -1.0f;
  out[O2 + e]      = keep ? w[e] : 0.0f;
  out[O8 + e]      = keep ? 1.0f : 0.0f;
}

__global__ void k_xout(const float* __restrict__ x, const float* __restrict__ permF,
                       const float* __restrict__ scoreP, float* __restrict__ out) {
  int i = blockIdx.x;
  int node = (int)permF[i];
  float s = scoreP[i];
  const float4* xr = (const float4*)&x[node * 256];
  float4* o = (float4*)&out[i * 256];
  float4 v = xr[threadIdx.x];
  o[threadIdx.x] = make_float4(v.x * s, v.y * s, v.z * s, v.w * s);
}

extern "C" void kernel_launch(void* const* d_in, const int* in_sizes, int n_in,
                              void* d_out, int out_size, void* d_ws, size_t ws_size,
                              hipStream_t stream) {
  (void)in_sizes; (void)n_in; (void)out_size; (void)d_ws; (void)ws_size;
  const float* x  = (const float*)d_in[0];
  const int*   ei = (const int*)d_in[1];
  const float* w  = (const float*)d_in[2];
  const float* W1 = (const float*)d_in[4];
  const float* b1 = (const float*)d_in[5];
  const float* W2 = (const float*)d_in[6];
  const float* b2 = (const float*)d_in[7];
  float* out    = (float*)d_out;
  unsigned short* yhi = (unsigned short*)out;                  // [32768*256] per chunk
  unsigned short* ylo = (unsigned short*)(out + YLO_OFF);
  unsigned long long* csr = (unsigned long long*)(out + CSR_OFF);
  float* dinv   = out + DINV_OFF;
  float* z      = out + Z_OFF;
  unsigned* rstart = (unsigned*)(out + RSTART_OFF);
  unsigned* cursor = (unsigned*)(out + CURSOR_OFF);
  unsigned long long* hist64 = (unsigned long long*)(out + HIST_OFF);
  unsigned short* w1hi = (unsigned short*)(out + W1HI_OFF);
  unsigned short* w1lo = (unsigned short*)(out + W1LO_OFF);
  float* score  = out + SCORE_OFF;
  int*   mask   = (int*)d_out;

  k_zero<<<256, 256, 0, stream>>>(hist64, z);
  k_hist<<<2048, 256, 0, stream>>>(ei, w, hist64);
  k_prefix<<<64, 256, 0, stream>>>(hist64, rstart, cursor, dinv);
  k_w1t<<<32, 256, 0, stream>>>(W1, w1hi, w1lo);
  k_scatter<<<2048, 256, 0, stream>>>(ei, w, dinv, cursor, csr);
  for (int ch = 0; ch < 2; ++ch) {
    k_aggx<<<512, 256, 0, stream>>>(x, csr, rstart, dinv, yhi, ylo, ch * 32);
    k_gemm<<<1024, 256, 0, stream>>>(yhi, ylo, w1hi, w1lo, b1, W2, z, ch * 32768);
  }
  k_score<<<256, 256, 0, stream>>>(csr, rstart, dinv, z, b2, score, mask);
  k_topk<<<64, 256, 0, stream>>>(score, mask, out);
  k_edges<<<2048, 256, 0, stream>>>(ei, w, mask, out);
  k_xout<<<30912, 64, 0, stream>>>(x, out + O4, out + O5, out);
}

// Round 10
// 316.032 us; speedup vs baseline: 1.2166x; 1.0076x over previous
//
#include <hip/hip_runtime.h>

// Problem constants
#define NN   65536      // N nodes
#define NE   524288     // E edges
#define EPG  8192       // edges per graph

// Output float offsets in d_out (total 10111552 floats)
#define O1 7913472      // ei_new (2*E)
#define O2 8962048      // ea_new (E)
#define O3 9486336      // batch_out (30912)
#define O4 9517248      // perm (30912)
#define O5 9548160      // score_perm (30912)
#define O6 9579072      // sentence_scores (4096)
#define O7 9583168      // sentence_batch (4096)
#define O8 9587264      // keep (E)

// Scratch placement (float offsets), lifetime-verified (same as R9):
//  yhi/ylo [0, 8388608)        die after last k_gemm
//  csr    [8388608, 9437184)   u64; dies after k_score (before k_edges O1/O2)
//  dinv   [9437184, 9502720)   dies after k_score
//  z      [9502720, 9568256)   dies after k_score (k_topk writes O4/O5 later)
//  w1hi   [9568256, 9633792)   dies after last k_gemm (before k_edges O8)
//  rstart [9633792, 9699329)   u32[65537]; dies after k_score
//  cursor [9699344, 9764880)   dies after k_scatter
//  w1lo   [9764880, 9830416)   dies after last k_gemm
//  hist64 [9830416, 9961488)   u64[65536]; dies after k_prefix (k_edges writes O8 last)
//  score  [65536, 131072)      written after y planes die; dies after k_topk
//  mask   ints [0, 65536)      written after GEMMs; read k_edges; k_xout overwrites last
#define CSR_OFF    8388608
#define DINV_OFF   9437184
#define Z_OFF      9502720
#define W1HI_OFF   9568256
#define RSTART_OFF 9633792
#define CURSOR_OFF 9699344
#define W1LO_OFF   9764880
#define HIST_OFF   9830416
#define SCORE_OFF  65536
#define YLO_OFF    4194304   // ushort-plane offsets: yhi at float 0, ylo at float 4194304

typedef __attribute__((ext_vector_type(8))) short bfrag;
typedef __attribute__((ext_vector_type(4))) float f32x4;
typedef __attribute__((ext_vector_type(8))) unsigned short us8;

__device__ __forceinline__ unsigned monof(float f) {
  unsigned u = __float_as_uint(f);
  return (u & 0x80000000u) ? ~u : (u | 0x80000000u);  // ascending monotone map
}

__device__ __forceinline__ unsigned short bf16rne(float f) {
  unsigned u = __float_as_uint(f);
  return (unsigned short)((u + 0x7FFFu + ((u >> 16) & 1u)) >> 16);
}

__global__ void k_zero(unsigned long long* __restrict__ hist, float* __restrict__ z) {
  int n = blockIdx.x * 256 + threadIdx.x;
  if (n < NN) { hist[n] = 0ull; z[n] = 0.0f; }
}

// One packed u64 atomic per edge: count in bits>=40, wsum fixed-point 2^-20 below.
__global__ void k_hist(const int* __restrict__ ei, const float* __restrict__ w,
                       unsigned long long* __restrict__ hist) {
  int e = blockIdx.x * 256 + threadIdx.x;
  if (e < NE) {
    int c = ei[NE + e];
    unsigned long long add = (1ull << 40) |
        (unsigned long long)(unsigned)__float2uint_rn(w[e] * 1048576.0f);
    atomicAdd(&hist[c], add);
  }
}

// Per graph: exclusive prefix over 1024 bins -> rstart/cursor; dinv from fixed-point wsum.
__global__ __launch_bounds__(256) void k_prefix(const unsigned long long* __restrict__ hist,
    unsigned* __restrict__ rstart, unsigned* __restrict__ cursor, float* __restrict__ dinv) {
  __shared__ unsigned tmp[2][256];
  int g = blockIdx.x, t = threadIdx.x;
  int base = g << 10;
  unsigned c[4], sum = 0;
  unsigned long long hv[4];
#pragma unroll
  for (int u = 0; u < 4; ++u) {
    hv[u] = hist[base + t * 4 + u];
    c[u] = (unsigned)(hv[u] >> 40);
    sum += c[u];
  }
  tmp[0][t] = sum;
  __syncthreads();
  int pin = 0;
  for (int off = 1; off < 256; off <<= 1) {
    int pout = pin ^ 1;
    unsigned v = tmp[pin][t];
    if (t >= off) v += tmp[pin][t - off];
    tmp[pout][t] = v;
    __syncthreads();
    pin = pout;
  }
  unsigned run = (t == 0) ? 0u : tmp[pin][t - 1];
#pragma unroll
  for (int u = 0; u < 4; ++u) {
    unsigned pos = (unsigned)(g << 13) + run;   // g*8192 + prefix
    rstart[base + t * 4 + u] = pos;
    cursor[base + t * 4 + u] = pos;
    run += c[u];
  }
#pragma unroll
  for (int u = 0; u < 4; ++u) {
    int n = base + t * 4 + u;
    float wsum = 1.0f + (float)(hv[u] & ((1ull << 40) - 1)) * 9.5367431640625e-07f;
    dinv[n] = rsqrtf(wsum);
  }
  if (g == 0 && t == 0) rstart[NN] = NE;
}

// Split+transpose W1 [256k][512c] fp32 -> w1hi/w1lo [512c][256k] bf16 (k-contiguous)
__global__ __launch_bounds__(256) void k_w1t(const float* __restrict__ W1,
    unsigned short* __restrict__ hi, unsigned short* __restrict__ lo) {
  __shared__ unsigned short sh[64][72], sl[64][72];
  int bk = blockIdx.x & 3, bc = blockIdx.x >> 2;
  int k0 = bk * 64, c0 = bc * 64;
  int t = threadIdx.x;
#pragma unroll
  for (int s = 0; s < 16; ++s) {
    int i = t + s * 256;
    int k = i >> 6, c = i & 63;
    float v = W1[(k0 + k) * 512 + c0 + c];
    unsigned short h = bf16rne(v);
    float hf = __uint_as_float((unsigned)h << 16);
    sh[c][k] = h;
    sl[c][k] = bf16rne(v - hf);
  }
  __syncthreads();
#pragma unroll
  for (int s = 0; s < 16; ++s) {
    int i = t + s * 256;
    int c = i >> 6, k = i & 63;
    hi[(c0 + c) * 256 + k0 + k] = sh[c][k];
    lo[(c0 + c) * 256 + k0 + k] = sl[c][k];
  }
}

// Scatter edges to dest-sorted CSR: csr[pos] = coef<<32 | dest_local<<16 | src_local
__global__ void k_scatter(const int* __restrict__ ei, const float* __restrict__ w,
                          const float* __restrict__ dinv, unsigned* __restrict__ cursor,
                          unsigned long long* __restrict__ csr) {
  int e = blockIdx.x * 256 + threadIdx.x;
  if (e < NE) {
    int r = ei[e], c = ei[NE + e];
    float cf = w[e] * dinv[r] * dinv[c];
    unsigned pos = atomicAdd(&cursor[c], 1u);
    csr[pos] = ((unsigned long long)__float_as_uint(cf) << 32) |
               ((unsigned)(c & 1023) << 16) | (unsigned)(r & 1023);
  }
}

// Aggregate x over normalized adjacency -> y bf16 hi/lo planes.
// Block = (graph g, 16-col chunk), 512 THREADS (32 groups x 16 lanes):
// same LDS/edge-visits as R9 but 2x waves/CU (16 waves/CU, 4/SIMD) to cover
// the VALU-issue bound. Each group owns 32 dests, runs pairs (d, d+16)
// batch-8 predicated (16 independent loads in flight).
__global__ __launch_bounds__(512, 4) void k_aggx(const float* __restrict__ x,
    const unsigned long long* __restrict__ csr, const unsigned* __restrict__ rstart,
    const float* __restrict__ dinv, unsigned short* __restrict__ yhi,
    unsigned short* __restrict__ ylo, int gbase) {
  __shared__ float xs[1024 * 17];   // 68 KB
  __shared__ unsigned rp[1025];
  __shared__ float dv2[1024];
  int bid = blockIdx.x;
  int g  = bid & 31;                // graph g -> XCD g%8 (L2 locality)
  int cc = bid >> 5;                // 16 chunks of 16 columns
  int gg = gbase + g;
  int c0 = cc * 16;
  int t = threadIdx.x;              // 0..511
  int nbase = gg << 10;
  for (int i = t; i < 1024; i += 512) {
    rp[i] = rstart[nbase + i];
    float dv = dinv[nbase + i];
    dv2[i] = dv * dv;
  }
  if (t == 0) rp[1024] = rstart[nbase + 1024];
  // stage x[:, c0:c0+16] via float4 loads (4096 slots / 512 threads)
#pragma unroll
  for (int s = 0; s < 8; ++s) {
    int i = t + s * 512;            // float4-slot: row = i>>2, quad = i&3
    int row = i >> 2, q = (i & 3) * 4;
    float4 v = *(const float4*)&x[(nbase + row) * 256 + c0 + q];
    float* d = &xs[row * 17 + q];
    d[0] = v.x; d[1] = v.y; d[2] = v.z; d[3] = v.w;
  }
  __syncthreads();
  int j = t & 15, grp = t >> 4;     // 32 groups of 16 lanes; lane j = column
  int dbase = grp * 32;             // group owns dests [dbase, dbase+32)
  for (int dd = 0; dd < 16; ++dd) {
    int d0 = dbase + dd, d1 = d0 + 16;
    unsigned p0 = rp[d0], q0 = rp[d0 + 1];
    unsigned p1 = rp[d1], q1 = rp[d1 + 1];
    int L0 = (int)(q0 - p0), L1 = (int)(q1 - p1);
    int L = L0 > L1 ? L0 : L1;
    int M0 = L0 > 0 ? L0 - 1 : 0;   // clamp limits
    int M1 = L1 > 0 ? L1 - 1 : 0;
    float a0 = dv2[d0] * xs[d0 * 17 + j];
    float a1 = dv2[d1] * xs[d1 * 17 + j];
    for (int k = 0; k < L; k += 8) {
      unsigned long long cb0[8], cb1[8];
#pragma unroll
      for (int u = 0; u < 8; ++u) {         // 16 independent loads in flight
        int i0 = k + u; i0 = i0 < M0 ? i0 : M0;
        int i1 = k + u; i1 = i1 < M1 ? i1 : M1;
        cb0[u] = csr[p0 + i0];
        cb1[u] = csr[p1 + i1];
      }
#pragma unroll
      for (int u = 0; u < 8; ++u) {
        int kk = k + u;
        float f0 = kk < L0 ? __uint_as_float((unsigned)(cb0[u] >> 32)) : 0.0f;
        float f1 = kk < L1 ? __uint_as_float((unsigned)(cb1[u] >> 32)) : 0.0f;
        a0 += f0 * xs[(unsigned)(cb0[u] & 1023) * 17 + j];
        a1 += f1 * xs[(unsigned)(cb1[u] & 1023) * 17 + j];
      }
    }
    int i0 = ((g << 10) + d0) * 256 + c0 + j;
    int i1 = ((g << 10) + d1) * 256 + c0 + j;
    unsigned short h0 = bf16rne(a0), h1 = bf16rne(a1);
    yhi[i0] = h0;
    ylo[i0] = bf16rne(a0 - __uint_as_float((unsigned)h0 << 16));
    yhi[i1] = h1;
    ylo[i1] = bf16rne(a1 - __uint_as_float((unsigned)h1 << 16));
  }
}

// MFMA GEMM: h = y(32768x256) @ W1(256x512) via bf16 hi/lo 3-product split,
// fused +b1 -> LeakyReLU -> dot W2 -> atomic z.  128x128 tile, 4 waves (64x64).
__global__ __launch_bounds__(256, 2) void k_gemm(
    const unsigned short* __restrict__ yhi, const unsigned short* __restrict__ ylo,
    const unsigned short* __restrict__ w1hi, const unsigned short* __restrict__ w1lo,
    const float* __restrict__ b1, const float* __restrict__ W2,
    float* __restrict__ z, int node_base) {
  __shared__ unsigned short Ah_s[128 * 40], Al_s[128 * 40];  // [row][40] ushort, 80B stride
  __shared__ unsigned short Bh_s[128 * 40], Bl_s[128 * 40];  // [col][40]
  int bx = blockIdx.x & 3, by = blockIdx.x >> 2;
  int r0 = by * 128, c0 = bx * 128;
  int t = threadIdx.x;
  int lane = t & 63, wid = t >> 6;
  int wr = wid >> 1, wc = wid & 1;         // wave tile origin (wr*64, wc*64)
  int lr = lane & 15, hg = lane >> 4;
  f32x4 acc[4][4];
#pragma unroll
  for (int m = 0; m < 4; ++m)
#pragma unroll
    for (int n = 0; n < 4; ++n)
      acc[m][n] = (f32x4){0.0f, 0.0f, 0.0f, 0.0f};
  int rr = t >> 2, kq = (t & 3) * 8;       // staging: rows rr, rr+64; 8-elem k-chunk
  for (int kt = 0; kt < 256; kt += 32) {
    us8 va0 = *(const us8*)&yhi[(r0 + rr) * 256 + kt + kq];
    us8 va1 = *(const us8*)&yhi[(r0 + rr + 64) * 256 + kt + kq];
    us8 vb0 = *(const us8*)&ylo[(r0 + rr) * 256 + kt + kq];
    us8 vb1 = *(const us8*)&ylo[(r0 + rr + 64) * 256 + kt + kq];
    us8 vc0 = *(const us8*)&w1hi[(c0 + rr) * 256 + kt + kq];
    us8 vc1 = *(const us8*)&w1hi[(c0 + rr + 64) * 256 + kt + kq];
    us8 vd0 = *(const us8*)&w1lo[(c0 + rr) * 256 + kt + kq];
    us8 vd1 = *(const us8*)&w1lo[(c0 + rr + 64) * 256 + kt + kq];
    __syncthreads();                        // prev-step frag reads complete
    *(us8*)&Ah_s[rr * 40 + kq] = va0;  *(us8*)&Ah_s[(rr + 64) * 40 + kq] = va1;
    *(us8*)&Al_s[rr * 40 + kq] = vb0;  *(us8*)&Al_s[(rr + 64) * 40 + kq] = vb1;
    *(us8*)&Bh_s[rr * 40 + kq] = vc0;  *(us8*)&Bh_s[(rr + 64) * 40 + kq] = vc1;
    *(us8*)&Bl_s[rr * 40 + kq] = vd0;  *(us8*)&Bl_s[(rr + 64) * 40 + kq] = vd1;
    __syncthreads();
    bfrag Ah[4], Al[4], Bh[4], Bl[4];
#pragma unroll
    for (int m = 0; m < 4; ++m) {
      int ra = (wr * 64 + m * 16 + lr) * 40 + hg * 8;
      Ah[m] = *(const bfrag*)&Ah_s[ra];
      Al[m] = *(const bfrag*)&Al_s[ra];
      int rb = (wc * 64 + m * 16 + lr) * 40 + hg * 8;
      Bh[m] = *(const bfrag*)&Bh_s[rb];
      Bl[m] = *(const bfrag*)&Bl_s[rb];
    }
#pragma unroll
    for (int m = 0; m < 4; ++m)
#pragma unroll
      for (int n = 0; n < 4; ++n) {
        acc[m][n] = __builtin_amdgcn_mfma_f32_16x16x32_bf16(Ah[m], Bh[n], acc[m][n], 0, 0, 0);
        acc[m][n] = __builtin_amdgcn_mfma_f32_16x16x32_bf16(Ah[m], Bl[n], acc[m][n], 0, 0, 0);
        acc[m][n] = __builtin_amdgcn_mfma_f32_16x16x32_bf16(Al[m], Bh[n], acc[m][n], 0, 0, 0);
      }
  }
  // epilogue: +b1, LeakyReLU, dot W2, reduce over the 16 col-lanes, atomic z
  float p[4][4];
#pragma unroll
  for (int m = 0; m < 4; ++m)
#pragma unroll
    for (int i = 0; i < 4; ++i) p[m][i] = 0.0f;
#pragma unroll
  for (int n = 0; n < 4; ++n) {
    int col = c0 + wc * 64 + n * 16 + lr;
    float b1v = b1[col], w2v = W2[col];
#pragma unroll
    for (int m = 0; m < 4; ++m)
#pragma unroll
      for (int i = 0; i < 4; ++i) {
        float v = acc[m][n][i] + b1v;
        v = v > 0.0f ? v : 0.01f * v;
        p[m][i] += v * w2v;
      }
  }
#pragma unroll
  for (int off = 8; off > 0; off >>= 1)
#pragma unroll
    for (int m = 0; m < 4; ++m)
#pragma unroll
      for (int i = 0; i < 4; ++i)
        p[m][i] += __shfl_xor(p[m][i], off, 16);
  if (lr == 0) {
    int rbase = node_base + r0 + wr * 64 + hg * 4;
#pragma unroll
    for (int m = 0; m < 4; ++m)
#pragma unroll
      for (int i = 0; i < 4; ++i)
        unsafeAtomicAdd(&z[rbase + m * 16 + i], p[m][i]);
  }
}

// score[n] = b2 + dinv[n]^2*z[n] + sum_{e in seg(n)} coef[e]*z[global_row]
// Also initializes mask[n] = -1 (fused, saves a launch).
__global__ void k_score(const unsigned long long* __restrict__ csr,
                        const unsigned* __restrict__ rstart,
                        const float* __restrict__ dinv, const float* __restrict__ z,
                        const float* __restrict__ b2, float* __restrict__ score,
                        int* __restrict__ mask) {
  int n = blockIdx.x * 256 + threadIdx.x;
  if (n >= NN) return;
  mask[n] = -1;
  int nb = n & ~1023;
  float dv = dinv[n];
  float a = b2[0] + dv * dv * z[n];
  unsigned s = rstart[n], epos = rstart[n + 1];
  for (unsigned e = s; e < epos; ++e) {
    unsigned long long p = csr[e];
    a += __uint_as_float((unsigned)(p >> 32)) * z[nb + (unsigned)(p & 1023)];
  }
  score[n] = a;
}

__device__ void bitonic(unsigned long long* keys, int n, int t, int nt) {
  for (int k = 2; k <= n; k <<= 1)
    for (int jj = k >> 1; jj > 0; jj >>= 1) {
      __syncthreads();
      for (int i = t; i < n; i += nt) {
        int ixj = i ^ jj;
        if (ixj > i) {
          unsigned long long a = keys[i], c = keys[ixj];
          bool up = ((i & k) == 0);
          if ((a > c) == up) { keys[i] = c; keys[ixj] = a; }
        }
      }
    }
  __syncthreads();
}

__global__ __launch_bounds__(256) void k_topk(const float* __restrict__ score,
                                              int* __restrict__ mask,
                                              float* __restrict__ out) {
  __shared__ unsigned long long keys[1024];
  int b = blockIdx.x, t = threadIdx.x;
  int base = b << 10;
  if (t < 64) {
    float v = score[base + t];
    keys[t] = ((unsigned long long)(~monof(v)) << 32) | (unsigned)t;
    out[O6 + b * 64 + t] = v;
    out[O7 + b * 64 + t] = (float)b;
  }
  __syncthreads();
  bitonic(keys, 64, t, 256);
  if (t < 3) {
    int idx = (int)(keys[t] & 0xFFFFFFFFull);
    int node = base + idx;
    int pos = b * 3 + t;
    mask[node] = pos;
    out[O4 + pos] = (float)node;
    out[O5 + pos] = score[node];
    out[O3 + pos] = (float)b;
  }
  __syncthreads();
  for (int i = t; i < 1024; i += 256) {
    if (i < 960) {
      float v = score[base + 64 + i];
      keys[i] = ((unsigned long long)(~monof(v)) << 32) | (unsigned)i;
    } else {
      keys[i] = 0xFFFFFFFFFFFFFFFFull;
    }
  }
  __syncthreads();
  bitonic(keys, 1024, t, 256);
  for (int r = t; r < 480; r += 256) {
    int idx = (int)(keys[r] & 0xFFFFFFFFull);
    int node = base + 64 + idx;
    int pos = 192 + b * 480 + r;
    mask[node] = pos;
    out[O4 + pos] = (float)node;
    out[O5 + pos] = score[node];
    out[O3 + pos] = (float)b;
  }
}

__global__ void k_edges(const int* __restrict__ ei, const float* __restrict__ w,
                        const int* __restrict__ mask, float* __restrict__ out) {
  int e = blockIdx.x * 256 + threadIdx.x;
  if (e >= NE) return;
  int nr = mask[ei[e]];
  int nc = mask[ei[NE + e]];
  bool keep = (nr >= 0) && (nc >= 0);
  out[O1 + e]      = keep ? (float)nr : -1.0f;
  out[O1 + NE + e] = keep ? (float)nc : -1.0f;
  out[O2 + e]      = keep ? w[e] : 0.0f;
  out[O8 + e]      = keep ? 1.0f : 0.0f;
}

__global__ void k_xout(const float* __restrict__ x, const float* __restrict__ permF,
                       const float* __restrict__ scoreP, float* __restrict__ out) {
  int i = blockIdx.x;
  int node = (int)permF[i];
  float s = scoreP[i];
  const float4* xr = (const float4*)&x[node * 256];
  float4* o = (float4*)&out[i * 256];
  float4 v = xr[threadIdx.x];
  o[threadIdx.x] = make_float4(v.x * s, v.y * s, v.z * s, v.w * s);
}

extern "C" void kernel_launch(void* const* d_in, const int* in_sizes, int n_in,
                              void* d_out, int out_size, void* d_ws, size_t ws_size,
                              hipStream_t stream) {
  (void)in_sizes; (void)n_in; (void)out_size; (void)d_ws; (void)ws_size;
  const float* x  = (const float*)d_in[0];
  const int*   ei = (const int*)d_in[1];
  const float* w  = (const float*)d_in[2];
  const float* W1 = (const float*)d_in[4];
  const float* b1 = (const float*)d_in[5];
  const float* W2 = (const float*)d_in[6];
  const float* b2 = (const float*)d_in[7];
  float* out    = (float*)d_out;
  unsigned short* yhi = (unsigned short*)out;                  // [32768*256] per chunk
  unsigned short* ylo = (unsigned short*)(out + YLO_OFF);
  unsigned long long* csr = (unsigned long long*)(out + CSR_OFF);
  float* dinv   = out + DINV_OFF;
  float* z      = out + Z_OFF;
  unsigned* rstart = (unsigned*)(out + RSTART_OFF);
  unsigned* cursor = (unsigned*)(out + CURSOR_OFF);
  unsigned long long* hist64 = (unsigned long long*)(out + HIST_OFF);
  unsigned short* w1hi = (unsigned short*)(out + W1HI_OFF);
  unsigned short* w1lo = (unsigned short*)(out + W1LO_OFF);
  float* score  = out + SCORE_OFF;
  int*   mask   = (int*)d_out;

  k_zero<<<256, 256, 0, stream>>>(hist64, z);
  k_hist<<<2048, 256, 0, stream>>>(ei, w, hist64);
  k_prefix<<<64, 256, 0, stream>>>(hist64, rstart, cursor, dinv);
  k_w1t<<<32, 256, 0, stream>>>(W1, w1hi, w1lo);
  k_scatter<<<2048, 256, 0, stream>>>(ei, w, dinv, cursor, csr);
  for (int ch = 0; ch < 2; ++ch) {
    k_aggx<<<512, 512, 0, stream>>>(x, csr, rstart, dinv, yhi, ylo, ch * 32);
    k_gemm<<<1024, 256, 0, stream>>>(yhi, ylo, w1hi, w1lo, b1, W2, z, ch * 32768);
  }
  k_score<<<256, 256, 0, stream>>>(csr, rstart, dinv, z, b2, score, mask);
  k_topk<<<64, 256, 0, stream>>>(score, mask, out);
  k_edges<<<2048, 256, 0, stream>>>(ei, w, mask, out);
  k_xout<<<30912, 64, 0, stream>>>(x, out + O4, out + O5, out);
}

// Round 11
// 301.209 us; speedup vs baseline: 1.2765x; 1.0492x over previous
//
#include <hip/hip_runtime.h>

// Problem constants
#define NN   65536      // N nodes
#define NE   524288     // E edges
#define EPG  8192       // edges per graph

// Output float offsets in d_out (total 10111552 floats)
#define O1 7913472      // ei_new (2*E)
#define O2 8962048      // ea_new (E)
#define O3 9486336      // batch_out (30912)
#define O4 9517248      // perm (30912)
#define O5 9548160      // score_perm (30912)
#define O6 9579072      // sentence_scores (4096)
#define O7 9583168      // sentence_batch (4096)
#define O8 9587264      // keep (E)

// Scratch placement (float offsets), lifetime-verified (same as R9/R10):
#define CSR_OFF    8388608
#define DINV_OFF   9437184
#define Z_OFF      9502720
#define W1HI_OFF   9568256
#define RSTART_OFF 9633792
#define CURSOR_OFF 9699344
#define W1LO_OFF   9764880
#define HIST_OFF   9830416
#define SCORE_OFF  65536
#define YLO_OFF    4194304   // ushort-plane offsets: yhi at float 0, ylo at float 4194304

typedef __attribute__((ext_vector_type(8))) short bfrag;
typedef __attribute__((ext_vector_type(4))) float f32x4;
typedef __attribute__((ext_vector_type(8))) unsigned short us8;

__device__ __forceinline__ unsigned monof(float f) {
  unsigned u = __float_as_uint(f);
  return (u & 0x80000000u) ? ~u : (u | 0x80000000u);  // ascending monotone map
}

__device__ __forceinline__ unsigned short bf16rne(float f) {
  unsigned u = __float_as_uint(f);
  return (unsigned short)((u + 0x7FFFu + ((u >> 16) & 1u)) >> 16);
}

__global__ void k_zero(unsigned long long* __restrict__ hist, float* __restrict__ z) {
  int n = blockIdx.x * 256 + threadIdx.x;
  if (n < NN) { hist[n] = 0ull; z[n] = 0.0f; }
}

// One packed u64 atomic per edge: count in bits>=40, wsum fixed-point 2^-20 below.
__global__ void k_hist(const int* __restrict__ ei, const float* __restrict__ w,
                       unsigned long long* __restrict__ hist) {
  int e = blockIdx.x * 256 + threadIdx.x;
  if (e < NE) {
    int c = ei[NE + e];
    unsigned long long add = (1ull << 40) |
        (unsigned long long)(unsigned)__float2uint_rn(w[e] * 1048576.0f);
    atomicAdd(&hist[c], add);
  }
}

// Per graph: exclusive prefix over 1024 bins -> rstart/cursor; dinv from fixed-point wsum.
__global__ __launch_bounds__(256) void k_prefix(const unsigned long long* __restrict__ hist,
    unsigned* __restrict__ rstart, unsigned* __restrict__ cursor, float* __restrict__ dinv) {
  __shared__ unsigned tmp[2][256];
  int g = blockIdx.x, t = threadIdx.x;
  int base = g << 10;
  unsigned c[4], sum = 0;
  unsigned long long hv[4];
#pragma unroll
  for (int u = 0; u < 4; ++u) {
    hv[u] = hist[base + t * 4 + u];
    c[u] = (unsigned)(hv[u] >> 40);
    sum += c[u];
  }
  tmp[0][t] = sum;
  __syncthreads();
  int pin = 0;
  for (int off = 1; off < 256; off <<= 1) {
    int pout = pin ^ 1;
    unsigned v = tmp[pin][t];
    if (t >= off) v += tmp[pin][t - off];
    tmp[pout][t] = v;
    __syncthreads();
    pin = pout;
  }
  unsigned run = (t == 0) ? 0u : tmp[pin][t - 1];
#pragma unroll
  for (int u = 0; u < 4; ++u) {
    unsigned pos = (unsigned)(g << 13) + run;   // g*8192 + prefix
    rstart[base + t * 4 + u] = pos;
    cursor[base + t * 4 + u] = pos;
    run += c[u];
  }
#pragma unroll
  for (int u = 0; u < 4; ++u) {
    int n = base + t * 4 + u;
    float wsum = 1.0f + (float)(hv[u] & ((1ull << 40) - 1)) * 9.5367431640625e-07f;
    dinv[n] = rsqrtf(wsum);
  }
  if (g == 0 && t == 0) rstart[NN] = NE;
}

// Split+transpose W1 [256k][512c] fp32 -> w1hi/w1lo [512c][256k] bf16 (k-contiguous)
__global__ __launch_bounds__(256) void k_w1t(const float* __restrict__ W1,
    unsigned short* __restrict__ hi, unsigned short* __restrict__ lo) {
  __shared__ unsigned short sh[64][72], sl[64][72];
  int bk = blockIdx.x & 3, bc = blockIdx.x >> 2;
  int k0 = bk * 64, c0 = bc * 64;
  int t = threadIdx.x;
#pragma unroll
  for (int s = 0; s < 16; ++s) {
    int i = t + s * 256;
    int k = i >> 6, c = i & 63;
    float v = W1[(k0 + k) * 512 + c0 + c];
    unsigned short h = bf16rne(v);
    float hf = __uint_as_float((unsigned)h << 16);
    sh[c][k] = h;
    sl[c][k] = bf16rne(v - hf);
  }
  __syncthreads();
#pragma unroll
  for (int s = 0; s < 16; ++s) {
    int i = t + s * 256;
    int c = i >> 6, k = i & 63;
    hi[(c0 + c) * 256 + k0 + k] = sh[c][k];
    lo[(c0 + c) * 256 + k0 + k] = sl[c][k];
  }
}

// Scatter edges to dest-sorted CSR: csr[pos] = coef<<32 | dest_local<<16 | src_local
__global__ void k_scatter(const int* __restrict__ ei, const float* __restrict__ w,
                          const float* __restrict__ dinv, unsigned* __restrict__ cursor,
                          unsigned long long* __restrict__ csr) {
  int e = blockIdx.x * 256 + threadIdx.x;
  if (e < NE) {
    int r = ei[e], c = ei[NE + e];
    float cf = w[e] * dinv[r] * dinv[c];
    unsigned pos = atomicAdd(&cursor[c], 1u);
    csr[pos] = ((unsigned long long)__float_as_uint(cf) << 32) |
               ((unsigned)(c & 1023) << 16) | (unsigned)(r & 1023);
  }
}

// Aggregate x over normalized adjacency -> y bf16 hi/lo planes.
// Block = (graph g, 32-col chunk), 512 threads, 140 KB LDS (1 block/CU).
// Halves edge-visits vs 16-col (2.1M/dispatch). 16 groups of 32 lanes;
// each group runs TWO dest segments (d, d+32) batch-4 predicated (proven
// R6 inner-loop structure). xs stride-33: 32-lane row read = 32 distinct banks.
__global__ __launch_bounds__(512, 2) void k_aggx(const float* __restrict__ x,
    const unsigned long long* __restrict__ csr, const unsigned* __restrict__ rstart,
    const float* __restrict__ dinv, unsigned short* __restrict__ yhi,
    unsigned short* __restrict__ ylo, int gbase) {
  __shared__ float xs[1024 * 33];   // 132 KB
  __shared__ unsigned rp[1025];
  __shared__ float dv2[1024];
  int bid = blockIdx.x;
  int g  = bid & 31;                // graph g -> XCD g%8 (L2 locality)
  int cc = bid >> 5;                // 8 chunks of 32 columns
  int gg = gbase + g;
  int c0 = cc * 32;
  int t = threadIdx.x;              // 0..511
  int nbase = gg << 10;
  for (int i = t; i < 1024; i += 512) {
    rp[i] = rstart[nbase + i];
    float dv = dinv[nbase + i];
    dv2[i] = dv * dv;
  }
  if (t == 0) rp[1024] = rstart[nbase + 1024];
  // stage x[:, c0:c0+32] via float4 loads (8192 slots / 512 threads)
#pragma unroll
  for (int s = 0; s < 16; ++s) {
    int i = t + s * 512;            // float4-slot: row = i>>3, quad = i&7
    int row = i >> 3, q = (i & 7) * 4;
    float4 v = *(const float4*)&x[(nbase + row) * 256 + c0 + q];
    float* d = &xs[row * 33 + q];
    d[0] = v.x; d[1] = v.y; d[2] = v.z; d[3] = v.w;
  }
  __syncthreads();
  int j = t & 31, grp = t >> 5;     // 16 groups of 32 lanes; lane j = column
  int dbase = grp * 64;             // group owns dests [dbase, dbase+64)
  for (int dd = 0; dd < 32; ++dd) {
    int d0 = dbase + dd, d1 = d0 + 32;
    unsigned p0 = rp[d0], q0 = rp[d0 + 1];
    unsigned p1 = rp[d1], q1 = rp[d1 + 1];
    int L0 = (int)(q0 - p0), L1 = (int)(q1 - p1);
    int L = L0 > L1 ? L0 : L1;
    float a0 = dv2[d0] * xs[d0 * 33 + j];
    float a1 = dv2[d1] * xs[d1 * 33 + j];
    for (int k = 0; k < L; k += 4) {
      unsigned long long cv0[4], cv1[4];
#pragma unroll
      for (int u = 0; u < 4; ++u) {
        int kk = k + u;
        cv0[u] = csr[kk < L0 ? p0 + kk : 0u];
        cv1[u] = csr[kk < L1 ? p1 + kk : 0u];
      }
#pragma unroll
      for (int u = 0; u < 4; ++u) {
        int kk = k + u;
        float f0 = kk < L0 ? __uint_as_float((unsigned)(cv0[u] >> 32)) : 0.0f;
        float f1 = kk < L1 ? __uint_as_float((unsigned)(cv1[u] >> 32)) : 0.0f;
        a0 += f0 * xs[(unsigned)(cv0[u] & 1023) * 33 + j];
        a1 += f1 * xs[(unsigned)(cv1[u] & 1023) * 33 + j];
      }
    }
    int i0 = ((g << 10) + d0) * 256 + c0 + j;
    int i1 = ((g << 10) + d1) * 256 + c0 + j;
    unsigned short h0 = bf16rne(a0), h1 = bf16rne(a1);
    yhi[i0] = h0;
    ylo[i0] = bf16rne(a0 - __uint_as_float((unsigned)h0 << 16));
    yhi[i1] = h1;
    ylo[i1] = bf16rne(a1 - __uint_as_float((unsigned)h1 << 16));
  }
}

// MFMA GEMM: h = y(32768x256) @ W1(256x512) via bf16 hi/lo 3-product split,
// fused +b1 -> LeakyReLU -> dot W2 -> atomic z.  128x128 tile, 4 waves (64x64).
__global__ __launch_bounds__(256, 2) void k_gemm(
    const unsigned short* __restrict__ yhi, const unsigned short* __restrict__ ylo,
    const unsigned short* __restrict__ w1hi, const unsigned short* __restrict__ w1lo,
    const float* __restrict__ b1, const float* __restrict__ W2,
    float* __restrict__ z, int node_base) {
  __shared__ unsigned short Ah_s[128 * 40], Al_s[128 * 40];  // [row][40] ushort, 80B stride
  __shared__ unsigned short Bh_s[128 * 40], Bl_s[128 * 40];  // [col][40]
  int bx = blockIdx.x & 3, by = blockIdx.x >> 2;
  int r0 = by * 128, c0 = bx * 128;
  int t = threadIdx.x;
  int lane = t & 63, wid = t >> 6;
  int wr = wid >> 1, wc = wid & 1;         // wave tile origin (wr*64, wc*64)
  int lr = lane & 15, hg = lane >> 4;
  f32x4 acc[4][4];
#pragma unroll
  for (int m = 0; m < 4; ++m)
#pragma unroll
    for (int n = 0; n < 4; ++n)
      acc[m][n] = (f32x4){0.0f, 0.0f, 0.0f, 0.0f};
  int rr = t >> 2, kq = (t & 3) * 8;       // staging: rows rr, rr+64; 8-elem k-chunk
  for (int kt = 0; kt < 256; kt += 32) {
    us8 va0 = *(const us8*)&yhi[(r0 + rr) * 256 + kt + kq];
    us8 va1 = *(const us8*)&yhi[(r0 + rr + 64) * 256 + kt + kq];
    us8 vb0 = *(const us8*)&ylo[(r0 + rr) * 256 + kt + kq];
    us8 vb1 = *(const us8*)&ylo[(r0 + rr + 64) * 256 + kt + kq];
    us8 vc0 = *(const us8*)&w1hi[(c0 + rr) * 256 + kt + kq];
    us8 vc1 = *(const us8*)&w1hi[(c0 + rr + 64) * 256 + kt + kq];
    us8 vd0 = *(const us8*)&w1lo[(c0 + rr) * 256 + kt + kq];
    us8 vd1 = *(const us8*)&w1lo[(c0 + rr + 64) * 256 + kt + kq];
    __syncthreads();                        // prev-step frag reads complete
    *(us8*)&Ah_s[rr * 40 + kq] = va0;  *(us8*)&Ah_s[(rr + 64) * 40 + kq] = va1;
    *(us8*)&Al_s[rr * 40 + kq] = vb0;  *(us8*)&Al_s[(rr + 64) * 40 + kq] = vb1;
    *(us8*)&Bh_s[rr * 40 + kq] = vc0;  *(us8*)&Bh_s[(rr + 64) * 40 + kq] = vc1;
    *(us8*)&Bl_s[rr * 40 + kq] = vd0;  *(us8*)&Bl_s[(rr + 64) * 40 + kq] = vd1;
    __syncthreads();
    bfrag Ah[4], Al[4], Bh[4], Bl[4];
#pragma unroll
    for (int m = 0; m < 4; ++m) {
      int ra = (wr * 64 + m * 16 + lr) * 40 + hg * 8;
      Ah[m] = *(const bfrag*)&Ah_s[ra];
      Al[m] = *(const bfrag*)&Al_s[ra];
      int rb = (wc * 64 + m * 16 + lr) * 40 + hg * 8;
      Bh[m] = *(const bfrag*)&Bh_s[rb];
      Bl[m] = *(const bfrag*)&Bl_s[rb];
    }
#pragma unroll
    for (int m = 0; m < 4; ++m)
#pragma unroll
      for (int n = 0; n < 4; ++n) {
        acc[m][n] = __builtin_amdgcn_mfma_f32_16x16x32_bf16(Ah[m], Bh[n], acc[m][n], 0, 0, 0);
        acc[m][n] = __builtin_amdgcn_mfma_f32_16x16x32_bf16(Ah[m], Bl[n], acc[m][n], 0, 0, 0);
        acc[m][n] = __builtin_amdgcn_mfma_f32_16x16x32_bf16(Al[m], Bh[n], acc[m][n], 0, 0, 0);
      }
  }
  // epilogue: +b1, LeakyReLU, dot W2, reduce over the 16 col-lanes, atomic z
  float p[4][4];
#pragma unroll
  for (int m = 0; m < 4; ++m)
#pragma unroll
    for (int i = 0; i < 4; ++i) p[m][i] = 0.0f;
#pragma unroll
  for (int n = 0; n < 4; ++n) {
    int col = c0 + wc * 64 + n * 16 + lr;
    float b1v = b1[col], w2v = W2[col];
#pragma unroll
    for (int m = 0; m < 4; ++m)
#pragma unroll
      for (int i = 0; i < 4; ++i) {
        float v = acc[m][n][i] + b1v;
        v = v > 0.0f ? v : 0.01f * v;
        p[m][i] += v * w2v;
      }
  }
#pragma unroll
  for (int off = 8; off > 0; off >>= 1)
#pragma unroll
    for (int m = 0; m < 4; ++m)
#pragma unroll
      for (int i = 0; i < 4; ++i)
        p[m][i] += __shfl_xor(p[m][i], off, 16);
  if (lr == 0) {
    int rbase = node_base + r0 + wr * 64 + hg * 4;
#pragma unroll
    for (int m = 0; m < 4; ++m)
#pragma unroll
      for (int i = 0; i < 4; ++i)
        unsafeAtomicAdd(&z[rbase + m * 16 + i], p[m][i]);
  }
}

// score[n] = b2 + dinv[n]^2*z[n] + sum_{e in seg(n)} coef[e]*z[global_row]
// Also initializes mask[n] = -1 (fused, saves a launch).
__global__ void k_score(const unsigned long long* __restrict__ csr,
                        const unsigned* __restrict__ rstart,
                        const float* __restrict__ dinv, const float* __restrict__ z,
                        const float* __restrict__ b2, float* __restrict__ score,
                        int* __restrict__ mask) {
  int n = blockIdx.x * 256 + threadIdx.x;
  if (n >= NN) return;
  mask[n] = -1;
  int nb = n & ~1023;
  float dv = dinv[n];
  float a = b2[0] + dv * dv * z[n];
  unsigned s = rstart[n], epos = rstart[n + 1];
  for (unsigned e = s; e < epos; ++e) {
    unsigned long long p = csr[e];
    a += __uint_as_float((unsigned)(p >> 32)) * z[nb + (unsigned)(p & 1023)];
  }
  score[n] = a;
}

__device__ void bitonic(unsigned long long* keys, int n, int t, int nt) {
  for (int k = 2; k <= n; k <<= 1)
    for (int jj = k >> 1; jj > 0; jj >>= 1) {
      __syncthreads();
      for (int i = t; i < n; i += nt) {
        int ixj = i ^ jj;
        if (ixj > i) {
          unsigned long long a = keys[i], c = keys[ixj];
          bool up = ((i & k) == 0);
          if ((a > c) == up) { keys[i] = c; keys[ixj] = a; }
        }
      }
    }
  __syncthreads();
}

__global__ __launch_bounds__(256) void k_topk(const float* __restrict__ score,
                                              int* __restrict__ mask,
                                              float* __restrict__ out) {
  __shared__ unsigned long long keys[1024];
  int b = blockIdx.x, t = threadIdx.x;
  int base = b << 10;
  if (t < 64) {
    float v = score[base + t];
    keys[t] = ((unsigned long long)(~monof(v)) << 32) | (unsigned)t;
    out[O6 + b * 64 + t] = v;
    out[O7 + b * 64 + t] = (float)b;
  }
  __syncthreads();
  bitonic(keys, 64, t, 256);
  if (t < 3) {
    int idx = (int)(keys[t] & 0xFFFFFFFFull);
    int node = base + idx;
    int pos = b * 3 + t;
    mask[node] = pos;
    out[O4 + pos] = (float)node;
    out[O5 + pos] = score[node];
    out[O3 + pos] = (float)b;
  }
  __syncthreads();
  for (int i = t; i < 1024; i += 256) {
    if (i < 960) {
      float v = score[base + 64 + i];
      keys[i] = ((unsigned long long)(~monof(v)) << 32) | (unsigned)i;
    } else {
      keys[i] = 0xFFFFFFFFFFFFFFFFull;
    }
  }
  __syncthreads();
  bitonic(keys, 1024, t, 256);
  for (int r = t; r < 480; r += 256) {
    int idx = (int)(keys[r] & 0xFFFFFFFFull);
    int node = base + 64 + idx;
    int pos = 192 + b * 480 + r;
    mask[node] = pos;
    out[O4 + pos] = (float)node;
    out[O5 + pos] = score[node];
    out[O3 + pos] = (float)b;
  }
}

__global__ void k_edges(const int* __restrict__ ei, const float* __restrict__ w,
                        const int* __restrict__ mask, float* __restrict__ out) {
  int e = blockIdx.x * 256 + threadIdx.x;
  if (e >= NE) return;
  int nr = mask[ei[e]];
  int nc = mask[ei[NE + e]];
  bool keep = (nr >= 0) && (nc >= 0);
  out[O1 + e]      = keep ? (float)nr : -1.0f;
  out[O1 + NE + e] = keep ? (float)nc : -1.0f;
  out[O2 + e]      = keep ? w[e] : 0.0f;
  out[O8 + e]      = keep ? 1.0f : 0.0f;
}

__global__ void k_xout(const float* __restrict__ x, const float* __restrict__ permF,
                       const float* __restrict__ scoreP, float* __restrict__ out) {
  int i = blockIdx.x;
  int node = (int)permF[i];
  float s = scoreP[i];
  const float4* xr = (const float4*)&x[node * 256];
  float4* o = (float4*)&out[i * 256];
  float4 v = xr[threadIdx.x];
  o[threadIdx.x] = make_float4(v.x * s, v.y * s, v.z * s, v.w * s);
}

extern "C" void kernel_launch(void* const* d_in, const int* in_sizes, int n_in,
                              void* d_out, int out_size, void* d_ws, size_t ws_size,
                              hipStream_t stream) {
  (void)in_sizes; (void)n_in; (void)out_size; (void)d_ws; (void)ws_size;
  const float* x  = (const float*)d_in[0];
  const int*   ei = (const int*)d_in[1];
  const float* w  = (const float*)d_in[2];
  const float* W1 = (const float*)d_in[4];
  const float* b1 = (const float*)d_in[5];
  const float* W2 = (const float*)d_in[6];
  const float* b2 = (const float*)d_in[7];
  float* out    = (float*)d_out;
  unsigned short* yhi = (unsigned short*)out;                  // [32768*256] per chunk
  unsigned short* ylo = (unsigned short*)(out + YLO_OFF);
  unsigned long long* csr = (unsigned long long*)(out + CSR_OFF);
  float* dinv   = out + DINV_OFF;
  float* z      = out + Z_OFF;
  unsigned* rstart = (unsigned*)(out + RSTART_OFF);
  unsigned* cursor = (unsigned*)(out + CURSOR_OFF);
  unsigned long long* hist64 = (unsigned long long*)(out + HIST_OFF);
  unsigned short* w1hi = (unsigned short*)(out + W1HI_OFF);
  unsigned short* w1lo = (unsigned short*)(out + W1LO_OFF);
  float* score  = out + SCORE_OFF;
  int*   mask   = (int*)d_out;

  k_zero<<<256, 256, 0, stream>>>(hist64, z);
  k_hist<<<2048, 256, 0, stream>>>(ei, w, hist64);
  k_prefix<<<64, 256, 0, stream>>>(hist64, rstart, cursor, dinv);
  k_w1t<<<32, 256, 0, stream>>>(W1, w1hi, w1lo);
  k_scatter<<<2048, 256, 0, stream>>>(ei, w, dinv, cursor, csr);
  for (int ch = 0; ch < 2; ++ch) {
    k_aggx<<<256, 512, 0, stream>>>(x, csr, rstart, dinv, yhi, ylo, ch * 32);
    k_gemm<<<1024, 256, 0, stream>>>(yhi, ylo, w1hi, w1lo, b1, W2, z, ch * 32768);
  }
  k_score<<<256, 256, 0, stream>>>(csr, rstart, dinv, z, b2, score, mask);
  k_topk<<<64, 256, 0, stream>>>(score, mask, out);
  k_edges<<<2048, 256, 0, stream>>>(ei, w, mask, out);
  k_xout<<<30912, 64, 0, stream>>>(x, out + O4, out + O5, out);
}

// Round 12
// 274.503 us; speedup vs baseline: 1.4007x; 1.0973x over previous
//
#include <hip/hip_runtime.h>

// Problem constants
#define NN   65536      // N nodes
#define NE   524288     // E edges
#define EPG  8192       // edges per graph

// Output float offsets in d_out (total 10111552 floats)
#define O1 7913472      // ei_new (2*E)
#define O2 8962048      // ea_new (E)
#define O3 9486336      // batch_out (30912)
#define O4 9517248      // perm (30912)
#define O5 9548160      // score_perm (30912)
#define O6 9579072      // sentence_scores (4096)
#define O7 9583168      // sentence_batch (4096)
#define O8 9587264      // keep (E)

// Scratch placement (float offsets), lifetime-verified (same as R9-R11):
#define CSR_OFF    8388608
#define DINV_OFF   9437184
#define Z_OFF      9502720
#define W1HI_OFF   9568256
#define RSTART_OFF 9633792
#define CURSOR_OFF 9699344
#define W1LO_OFF   9764880
#define HIST_OFF   9830416
#define SCORE_OFF  65536
#define YLO_OFF    4194304   // ushort-plane offsets: yhi at float 0, ylo at float 4194304

typedef __attribute__((ext_vector_type(8))) short bfrag;
typedef __attribute__((ext_vector_type(4))) float f32x4;
typedef __attribute__((ext_vector_type(8))) unsigned short us8;
typedef __attribute__((ext_vector_type(2))) unsigned long long u64x2;

__device__ __forceinline__ unsigned monof(float f) {
  unsigned u = __float_as_uint(f);
  return (u & 0x80000000u) ? ~u : (u | 0x80000000u);  // ascending monotone map
}

__device__ __forceinline__ unsigned short bf16rne(float f) {
  unsigned u = __float_as_uint(f);
  return (unsigned short)((u + 0x7FFFu + ((u >> 16) & 1u)) >> 16);
}

__global__ void k_zero(unsigned long long* __restrict__ hist, float* __restrict__ z) {
  int n = blockIdx.x * 256 + threadIdx.x;
  if (n < NN) { hist[n] = 0ull; z[n] = 0.0f; }
}

// One packed u64 atomic per edge: count in bits>=40, wsum fixed-point 2^-20 below.
__global__ void k_hist(const int* __restrict__ ei, const float* __restrict__ w,
                       unsigned long long* __restrict__ hist) {
  int e = blockIdx.x * 256 + threadIdx.x;
  if (e < NE) {
    int c = ei[NE + e];
    unsigned long long add = (1ull << 40) |
        (unsigned long long)(unsigned)__float2uint_rn(w[e] * 1048576.0f);
    atomicAdd(&hist[c], add);
  }
}

// Per graph: exclusive prefix over 1024 bins -> rstart/cursor; dinv from fixed-point wsum.
__global__ __launch_bounds__(256) void k_prefix(const unsigned long long* __restrict__ hist,
    unsigned* __restrict__ rstart, unsigned* __restrict__ cursor, float* __restrict__ dinv) {
  __shared__ unsigned tmp[2][256];
  int g = blockIdx.x, t = threadIdx.x;
  int base = g << 10;
  unsigned c[4], sum = 0;
  unsigned long long hv[4];
#pragma unroll
  for (int u = 0; u < 4; ++u) {
    hv[u] = hist[base + t * 4 + u];
    c[u] = (unsigned)(hv[u] >> 40);
    sum += c[u];
  }
  tmp[0][t] = sum;
  __syncthreads();
  int pin = 0;
  for (int off = 1; off < 256; off <<= 1) {
    int pout = pin ^ 1;
    unsigned v = tmp[pin][t];
    if (t >= off) v += tmp[pin][t - off];
    tmp[pout][t] = v;
    __syncthreads();
    pin = pout;
  }
  unsigned run = (t == 0) ? 0u : tmp[pin][t - 1];
#pragma unroll
  for (int u = 0; u < 4; ++u) {
    unsigned pos = (unsigned)(g << 13) + run;   // g*8192 + prefix
    rstart[base + t * 4 + u] = pos;
    cursor[base + t * 4 + u] = pos;
    run += c[u];
  }
#pragma unroll
  for (int u = 0; u < 4; ++u) {
    int n = base + t * 4 + u;
    float wsum = 1.0f + (float)(hv[u] & ((1ull << 40) - 1)) * 9.5367431640625e-07f;
    dinv[n] = rsqrtf(wsum);
  }
  if (g == 0 && t == 0) rstart[NN] = NE;
}

// Split+transpose W1 [256k][512c] fp32 -> w1hi/w1lo [512c][256k] bf16 (k-contiguous)
__global__ __launch_bounds__(256) void k_w1t(const float* __restrict__ W1,
    unsigned short* __restrict__ hi, unsigned short* __restrict__ lo) {
  __shared__ unsigned short sh[64][72], sl[64][72];
  int bk = blockIdx.x & 3, bc = blockIdx.x >> 2;
  int k0 = bk * 64, c0 = bc * 64;
  int t = threadIdx.x;
#pragma unroll
  for (int s = 0; s < 16; ++s) {
    int i = t + s * 256;
    int k = i >> 6, c = i & 63;
    float v = W1[(k0 + k) * 512 + c0 + c];
    unsigned short h = bf16rne(v);
    float hf = __uint_as_float((unsigned)h << 16);
    sh[c][k] = h;
    sl[c][k] = bf16rne(v - hf);
  }
  __syncthreads();
#pragma unroll
  for (int s = 0; s < 16; ++s) {
    int i = t + s * 256;
    int c = i >> 6, k = i & 63;
    hi[(c0 + c) * 256 + k0 + k] = sh[c][k];
    lo[(c0 + c) * 256 + k0 + k] = sl[c][k];
  }
}

// Scatter edges to dest-sorted CSR: csr[pos] = coef<<32 | dest_local<<16 | src_local
__global__ void k_scatter(const int* __restrict__ ei, const float* __restrict__ w,
                          const float* __restrict__ dinv, unsigned* __restrict__ cursor,
                          unsigned long long* __restrict__ csr) {
  int e = blockIdx.x * 256 + threadIdx.x;
  if (e < NE) {
    int r = ei[e], c = ei[NE + e];
    float cf = w[e] * dinv[r] * dinv[c];
    unsigned pos = atomicAdd(&cursor[c], 1u);
    csr[pos] = ((unsigned long long)__float_as_uint(cf) << 32) |
               ((unsigned)(c & 1023) << 16) | (unsigned)(r & 1023);
  }
}

// Aggregate x over normalized adjacency -> y bf16 hi/lo planes.
// Block = (graph g, 16-col chunk), 512 threads, ~140 KB LDS (1 block/CU).
// KEY: the graph's ENTIRE CSR (8192 edges, 64 KB) is staged into LDS with
// per-lane coalesced 16B loads (~64 load-instrs/block), so the inner loop
// has ZERO global loads -- only pipelineable ds_reads. Inner loop is the
// proven R10 structure verbatim (32 groups x 16 lanes, pairs (d,d+16),
// batch-4 predicated).
__global__ __launch_bounds__(512, 1) void k_aggx(const float* __restrict__ x,
    const unsigned long long* __restrict__ csr, const unsigned* __restrict__ rstart,
    const float* __restrict__ dinv, unsigned short* __restrict__ yhi,
    unsigned short* __restrict__ ylo, int gbase) {
  __shared__ float xs[1024 * 17];          // 68 KB
  __shared__ unsigned long long es[8192];  // 64 KB: whole graph's CSR
  __shared__ unsigned rp[1025];            // local (0..8192) segment starts
  __shared__ float dv2[1024];
  int bid = blockIdx.x;
  int g  = bid & 31;                // graph g -> XCD g%8 (L2 locality)
  int cc = bid >> 5;                // 16 chunks of 16 columns
  int gg = gbase + g;
  int c0 = cc * 16;
  int t = threadIdx.x;              // 0..511
  int nbase = gg << 10;
  unsigned ebase = (unsigned)gg << 13;
  for (int i = t; i < 1024; i += 512) {
    rp[i] = rstart[nbase + i] - ebase;
    float dv = dinv[nbase + i];
    dv2[i] = dv * dv;
  }
  if (t == 0) rp[1024] = 8192u;
  // stage whole-graph CSR: 8192 u64 via 16B per-lane loads (8 per thread)
  {
    const u64x2* src = (const u64x2*)(csr + ebase);
    u64x2* dst = (u64x2*)es;
#pragma unroll
    for (int i = 0; i < 8; ++i)
      dst[t + i * 512] = src[t + i * 512];
  }
  // stage x[:, c0:c0+16] via float4 loads (4096 slots / 512 threads)
#pragma unroll
  for (int s = 0; s < 8; ++s) {
    int i = t + s * 512;            // float4-slot: row = i>>2, quad = i&3
    int row = i >> 2, q = (i & 3) * 4;
    float4 v = *(const float4*)&x[(nbase + row) * 256 + c0 + q];
    float* d = &xs[row * 17 + q];
    d[0] = v.x; d[1] = v.y; d[2] = v.z; d[3] = v.w;
  }
  __syncthreads();
  int j = t & 15, grp = t >> 4;     // 32 groups of 16 lanes; lane j = column
  int dbase = grp * 32;             // group owns dests [dbase, dbase+32)
  for (int dd = 0; dd < 16; ++dd) {
    int d0 = dbase + dd, d1 = d0 + 16;
    unsigned p0 = rp[d0], q0 = rp[d0 + 1];
    unsigned p1 = rp[d1], q1 = rp[d1 + 1];
    int L0 = (int)(q0 - p0), L1 = (int)(q1 - p1);
    int L = L0 > L1 ? L0 : L1;
    int M0 = L0 > 0 ? L0 - 1 : 0;   // clamp limits
    int M1 = L1 > 0 ? L1 - 1 : 0;
    float a0 = dv2[d0] * xs[d0 * 17 + j];
    float a1 = dv2[d1] * xs[d1 * 17 + j];
    for (int k = 0; k < L; k += 4) {
      unsigned long long cv0[4], cv1[4];
#pragma unroll
      for (int u = 0; u < 4; ++u) {
        int kk = k + u;
        int i0 = kk < M0 ? kk : M0;
        int i1 = kk < M1 ? kk : M1;
        cv0[u] = es[p0 + i0];
        cv1[u] = es[p1 + i1];
      }
#pragma unroll
      for (int u = 0; u < 4; ++u) {
        int kk = k + u;
        float f0 = kk < L0 ? __uint_as_float((unsigned)(cv0[u] >> 32)) : 0.0f;
        float f1 = kk < L1 ? __uint_as_float((unsigned)(cv1[u] >> 32)) : 0.0f;
        a0 += f0 * xs[(unsigned)(cv0[u] & 1023) * 17 + j];
        a1 += f1 * xs[(unsigned)(cv1[u] & 1023) * 17 + j];
      }
    }
    int i0 = ((g << 10) + d0) * 256 + c0 + j;
    int i1 = ((g << 10) + d1) * 256 + c0 + j;
    unsigned short h0 = bf16rne(a0), h1 = bf16rne(a1);
    yhi[i0] = h0;
    ylo[i0] = bf16rne(a0 - __uint_as_float((unsigned)h0 << 16));
    yhi[i1] = h1;
    ylo[i1] = bf16rne(a1 - __uint_as_float((unsigned)h1 << 16));
  }
}

// MFMA GEMM: h = y(32768x256) @ W1(256x512) via bf16 hi/lo 3-product split,
// fused +b1 -> LeakyReLU -> dot W2 -> atomic z.  128x128 tile, 4 waves (64x64).
__global__ __launch_bounds__(256, 2) void k_gemm(
    const unsigned short* __restrict__ yhi, const unsigned short* __restrict__ ylo,
    const unsigned short* __restrict__ w1hi, const unsigned short* __restrict__ w1lo,
    const float* __restrict__ b1, const float* __restrict__ W2,
    float* __restrict__ z, int node_base) {
  __shared__ unsigned short Ah_s[128 * 40], Al_s[128 * 40];  // [row][40] ushort, 80B stride
  __shared__ unsigned short Bh_s[128 * 40], Bl_s[128 * 40];  // [col][40]
  int bx = blockIdx.x & 3, by = blockIdx.x >> 2;
  int r0 = by * 128, c0 = bx * 128;
  int t = threadIdx.x;
  int lane = t & 63, wid = t >> 6;
  int wr = wid >> 1, wc = wid & 1;         // wave tile origin (wr*64, wc*64)
  int lr = lane & 15, hg = lane >> 4;
  f32x4 acc[4][4];
#pragma unroll
  for (int m = 0; m < 4; ++m)
#pragma unroll
    for (int n = 0; n < 4; ++n)
      acc[m][n] = (f32x4){0.0f, 0.0f, 0.0f, 0.0f};
  int rr = t >> 2, kq = (t & 3) * 8;       // staging: rows rr, rr+64; 8-elem k-chunk
  for (int kt = 0; kt < 256; kt += 32) {
    us8 va0 = *(const us8*)&yhi[(r0 + rr) * 256 + kt + kq];
    us8 va1 = *(const us8*)&yhi[(r0 + rr + 64) * 256 + kt + kq];
    us8 vb0 = *(const us8*)&ylo[(r0 + rr) * 256 + kt + kq];
    us8 vb1 = *(const us8*)&ylo[(r0 + rr + 64) * 256 + kt + kq];
    us8 vc0 = *(const us8*)&w1hi[(c0 + rr) * 256 + kt + kq];
    us8 vc1 = *(const us8*)&w1hi[(c0 + rr + 64) * 256 + kt + kq];
    us8 vd0 = *(const us8*)&w1lo[(c0 + rr) * 256 + kt + kq];
    us8 vd1 = *(const us8*)&w1lo[(c0 + rr + 64) * 256 + kt + kq];
    __syncthreads();                        // prev-step frag reads complete
    *(us8*)&Ah_s[rr * 40 + kq] = va0;  *(us8*)&Ah_s[(rr + 64) * 40 + kq] = va1;
    *(us8*)&Al_s[rr * 40 + kq] = vb0;  *(us8*)&Al_s[(rr + 64) * 40 + kq] = vb1;
    *(us8*)&Bh_s[rr * 40 + kq] = vc0;  *(us8*)&Bh_s[(rr + 64) * 40 + kq] = vc1;
    *(us8*)&Bl_s[rr * 40 + kq] = vd0;  *(us8*)&Bl_s[(rr + 64) * 40 + kq] = vd1;
    __syncthreads();
    bfrag Ah[4], Al[4], Bh[4], Bl[4];
#pragma unroll
    for (int m = 0; m < 4; ++m) {
      int ra = (wr * 64 + m * 16 + lr) * 40 + hg * 8;
      Ah[m] = *(const bfrag*)&Ah_s[ra];
      Al[m] = *(const bfrag*)&Al_s[ra];
      int rb = (wc * 64 + m * 16 + lr) * 40 + hg * 8;
      Bh[m] = *(const bfrag*)&Bh_s[rb];
      Bl[m] = *(const bfrag*)&Bl_s[rb];
    }
#pragma unroll
    for (int m = 0; m < 4; ++m)
#pragma unroll
      for (int n = 0; n < 4; ++n) {
        acc[m][n] = __builtin_amdgcn_mfma_f32_16x16x32_bf16(Ah[m], Bh[n], acc[m][n], 0, 0, 0);
        acc[m][n] = __builtin_amdgcn_mfma_f32_16x16x32_bf16(Ah[m], Bl[n], acc[m][n], 0, 0, 0);
        acc[m][n] = __builtin_amdgcn_mfma_f32_16x16x32_bf16(Al[m], Bh[n], acc[m][n], 0, 0, 0);
      }
  }
  // epilogue: +b1, LeakyReLU, dot W2, reduce over the 16 col-lanes, atomic z
  float p[4][4];
#pragma unroll
  for (int m = 0; m < 4; ++m)
#pragma unroll
    for (int i = 0; i < 4; ++i) p[m][i] = 0.0f;
#pragma unroll
  for (int n = 0; n < 4; ++n) {
    int col = c0 + wc * 64 + n * 16 + lr;
    float b1v = b1[col], w2v = W2[col];
#pragma unroll
    for (int m = 0; m < 4; ++m)
#pragma unroll
      for (int i = 0; i < 4; ++i) {
        float v = acc[m][n][i] + b1v;
        v = v > 0.0f ? v : 0.01f * v;
        p[m][i] += v * w2v;
      }
  }
#pragma unroll
  for (int off = 8; off > 0; off >>= 1)
#pragma unroll
    for (int m = 0; m < 4; ++m)
#pragma unroll
      for (int i = 0; i < 4; ++i)
        p[m][i] += __shfl_xor(p[m][i], off, 16);
  if (lr == 0) {
    int rbase = node_base + r0 + wr * 64 + hg * 4;
#pragma unroll
    for (int m = 0; m < 4; ++m)
#pragma unroll
      for (int i = 0; i < 4; ++i)
        unsafeAtomicAdd(&z[rbase + m * 16 + i], p[m][i]);
  }
}

// score[n] = b2 + dinv[n]^2*z[n] + sum_{e in seg(n)} coef[e]*z[global_row]
// Also initializes mask[n] = -1 (fused, saves a launch).
__global__ void k_score(const unsigned long long* __restrict__ csr,
                        const unsigned* __restrict__ rstart,
                        const float* __restrict__ dinv, const float* __restrict__ z,
                        const float* __restrict__ b2, float* __restrict__ score,
                        int* __restrict__ mask) {
  int n = blockIdx.x * 256 + threadIdx.x;
  if (n >= NN) return;
  mask[n] = -1;
  int nb = n & ~1023;
  float dv = dinv[n];
  float a = b2[0] + dv * dv * z[n];
  unsigned s = rstart[n], epos = rstart[n + 1];
  for (unsigned e = s; e < epos; ++e) {
    unsigned long long p = csr[e];
    a += __uint_as_float((unsigned)(p >> 32)) * z[nb + (unsigned)(p & 1023)];
  }
  score[n] = a;
}

__device__ void bitonic(unsigned long long* keys, int n, int t, int nt) {
  for (int k = 2; k <= n; k <<= 1)
    for (int jj = k >> 1; jj > 0; jj >>= 1) {
      __syncthreads();
      for (int i = t; i < n; i += nt) {
        int ixj = i ^ jj;
        if (ixj > i) {
          unsigned long long a = keys[i], c = keys[ixj];
          bool up = ((i & k) == 0);
          if ((a > c) == up) { keys[i] = c; keys[ixj] = a; }
        }
      }
    }
  __syncthreads();
}

__global__ __launch_bounds__(256) void k_topk(const float* __restrict__ score,
                                              int* __restrict__ mask,
                                              float* __restrict__ out) {
  __shared__ unsigned long long keys[1024];
  int b = blockIdx.x, t = threadIdx.x;
  int base = b << 10;
  if (t < 64) {
    float v = score[base + t];
    keys[t] = ((unsigned long long)(~monof(v)) << 32) | (unsigned)t;
    out[O6 + b * 64 + t] = v;
    out[O7 + b * 64 + t] = (float)b;
  }
  __syncthreads();
  bitonic(keys, 64, t, 256);
  if (t < 3) {
    int idx = (int)(keys[t] & 0xFFFFFFFFull);
    int node = base + idx;
    int pos = b * 3 + t;
    mask[node] = pos;
    out[O4 + pos] = (float)node;
    out[O5 + pos] = score[node];
    out[O3 + pos] = (float)b;
  }
  __syncthreads();
  for (int i = t; i < 1024; i += 256) {
    if (i < 960) {
      float v = score[base + 64 + i];
      keys[i] = ((unsigned long long)(~monof(v)) << 32) | (unsigned)i;
    } else {
      keys[i] = 0xFFFFFFFFFFFFFFFFull;
    }
  }
  __syncthreads();
  bitonic(keys, 1024, t, 256);
  for (int r = t; r < 480; r += 256) {
    int idx = (int)(keys[r] & 0xFFFFFFFFull);
    int node = base + 64 + idx;
    int pos = 192 + b * 480 + r;
    mask[node] = pos;
    out[O4 + pos] = (float)node;
    out[O5 + pos] = score[node];
    out[O3 + pos] = (float)b;
  }
}

__global__ void k_edges(const int* __restrict__ ei, const float* __restrict__ w,
                        const int* __restrict__ mask, float* __restrict__ out) {
  int e = blockIdx.x * 256 + threadIdx.x;
  if (e >= NE) return;
  int nr = mask[ei[e]];
  int nc = mask[ei[NE + e]];
  bool keep = (nr >= 0) && (nc >= 0);
  out[O1 + e]      = keep ? (float)nr : -1.0f;
  out[O1 + NE + e] = keep ? (float)nc : -1.0f;
  out[O2 + e]      = keep ? w[e] : 0.0f;
  out[O8 + e]      = keep ? 1.0f : 0.0f;
}

__global__ void k_xout(const float* __restrict__ x, const float* __restrict__ permF,
                       const float* __restrict__ scoreP, float* __restrict__ out) {
  int i = blockIdx.x;
  int node = (int)permF[i];
  float s = scoreP[i];
  const float4* xr = (const float4*)&x[node * 256];
  float4* o = (float4*)&out[i * 256];
  float4 v = xr[threadIdx.x];
  o[threadIdx.x] = make_float4(v.x * s, v.y * s, v.z * s, v.w * s);
}

extern "C" void kernel_launch(void* const* d_in, const int* in_sizes, int n_in,
                              void* d_out, int out_size, void* d_ws, size_t ws_size,
                              hipStream_t stream) {
  (void)in_sizes; (void)n_in; (void)out_size; (void)d_ws; (void)ws_size;
  const float* x  = (const float*)d_in[0];
  const int*   ei = (const int*)d_in[1];
  const float* w  = (const float*)d_in[2];
  const float* W1 = (const float*)d_in[4];
  const float* b1 = (const float*)d_in[5];
  const float* W2 = (const float*)d_in[6];
  const float* b2 = (const float*)d_in[7];
  float* out    = (float*)d_out;
  unsigned short* yhi = (unsigned short*)out;                  // [32768*256] per chunk
  unsigned short* ylo = (unsigned short*)(out + YLO_OFF);
  unsigned long long* csr = (unsigned long long*)(out + CSR_OFF);
  float* dinv   = out + DINV_OFF;
  float* z      = out + Z_OFF;
  unsigned* rstart = (unsigned*)(out + RSTART_OFF);
  unsigned* cursor = (unsigned*)(out + CURSOR_OFF);
  unsigned long long* hist64 = (unsigned long long*)(out + HIST_OFF);
  unsigned short* w1hi = (unsigned short*)(out + W1HI_OFF);
  unsigned short* w1lo = (unsigned short*)(out + W1LO_OFF);
  float* score  = out + SCORE_OFF;
  int*   mask   = (int*)d_out;

  k_zero<<<256, 256, 0, stream>>>(hist64, z);
  k_hist<<<2048, 256, 0, stream>>>(ei, w, hist64);
  k_prefix<<<64, 256, 0, stream>>>(hist64, rstart, cursor, dinv);
  k_w1t<<<32, 256, 0, stream>>>(W1, w1hi, w1lo);
  k_scatter<<<2048, 256, 0, stream>>>(ei, w, dinv, cursor, csr);
  for (int ch = 0; ch < 2; ++ch) {
    k_aggx<<<512, 512, 0, stream>>>(x, csr, rstart, dinv, yhi, ylo, ch * 32);
    k_gemm<<<1024, 256, 0, stream>>>(yhi, ylo, w1hi, w1lo, b1, W2, z, ch * 32768);
  }
  k_score<<<256, 256, 0, stream>>>(csr, rstart, dinv, z, b2, score, mask);
  k_topk<<<64, 256, 0, stream>>>(score, mask, out);
  k_edges<<<2048, 256, 0, stream>>>(ei, w, mask, out);
  k_xout<<<30912, 64, 0, stream>>>(x, out + O4, out + O5, out);
}

// Round 13
// 259.451 us; speedup vs baseline: 1.4819x; 1.0580x over previous
//
#include <hip/hip_runtime.h>

// Problem constants
#define NN   65536      // N nodes
#define NE   524288     // E edges
#define EPG  8192       // edges per graph

// Output float offsets in d_out (total 10111552 floats)
#define O1 7913472      // ei_new (2*E)
#define O2 8962048      // ea_new (E)
#define O3 9486336      // batch_out (30912)
#define O4 9517248      // perm (30912)
#define O5 9548160      // score_perm (30912)
#define O6 9579072      // sentence_scores (4096)
#define O7 9583168      // sentence_batch (4096)
#define O8 9587264      // keep (E)

// Scratch placement (float offsets), lifetime-verified (same as R9-R12):
#define CSR_OFF    8388608
#define DINV_OFF   9437184
#define Z_OFF      9502720
#define W1HI_OFF   9568256
#define RSTART_OFF 9633792
#define CURSOR_OFF 9699344
#define W1LO_OFF   9764880
#define HIST_OFF   9830416
#define SCORE_OFF  65536
#define YLO_OFF    4194304   // ushort-plane offsets: yhi at float 0, ylo at float 4194304

typedef __attribute__((ext_vector_type(8))) short bfrag;
typedef __attribute__((ext_vector_type(4))) float f32x4;
typedef __attribute__((ext_vector_type(8))) unsigned short us8;
typedef __attribute__((ext_vector_type(2))) unsigned long long u64x2;

__device__ __forceinline__ unsigned monof(float f) {
  unsigned u = __float_as_uint(f);
  return (u & 0x80000000u) ? ~u : (u | 0x80000000u);  // ascending monotone map
}

__device__ __forceinline__ unsigned short bf16rne(float f) {
  unsigned u = __float_as_uint(f);
  return (unsigned short)((u + 0x7FFFu + ((u >> 16) & 1u)) >> 16);
}

__global__ void k_zero(unsigned long long* __restrict__ hist, float* __restrict__ z) {
  int n = blockIdx.x * 256 + threadIdx.x;
  if (n < NN) { hist[n] = 0ull; z[n] = 0.0f; }
}

// One packed u64 atomic per edge: count in bits>=40, wsum fixed-point 2^-20 below.
__global__ void k_hist(const int* __restrict__ ei, const float* __restrict__ w,
                       unsigned long long* __restrict__ hist) {
  int e = blockIdx.x * 256 + threadIdx.x;
  if (e < NE) {
    int c = ei[NE + e];
    unsigned long long add = (1ull << 40) |
        (unsigned long long)(unsigned)__float2uint_rn(w[e] * 1048576.0f);
    atomicAdd(&hist[c], add);
  }
}

// Per graph: exclusive prefix over 1024 bins -> rstart/cursor; dinv from fixed-point wsum.
__global__ __launch_bounds__(256) void k_prefix(const unsigned long long* __restrict__ hist,
    unsigned* __restrict__ rstart, unsigned* __restrict__ cursor, float* __restrict__ dinv) {
  __shared__ unsigned tmp[2][256];
  int g = blockIdx.x, t = threadIdx.x;
  int base = g << 10;
  unsigned c[4], sum = 0;
  unsigned long long hv[4];
#pragma unroll
  for (int u = 0; u < 4; ++u) {
    hv[u] = hist[base + t * 4 + u];
    c[u] = (unsigned)(hv[u] >> 40);
    sum += c[u];
  }
  tmp[0][t] = sum;
  __syncthreads();
  int pin = 0;
  for (int off = 1; off < 256; off <<= 1) {
    int pout = pin ^ 1;
    unsigned v = tmp[pin][t];
    if (t >= off) v += tmp[pin][t - off];
    tmp[pout][t] = v;
    __syncthreads();
    pin = pout;
  }
  unsigned run = (t == 0) ? 0u : tmp[pin][t - 1];
#pragma unroll
  for (int u = 0; u < 4; ++u) {
    unsigned pos = (unsigned)(g << 13) + run;   // g*8192 + prefix
    rstart[base + t * 4 + u] = pos;
    cursor[base + t * 4 + u] = pos;
    run += c[u];
  }
#pragma unroll
  for (int u = 0; u < 4; ++u) {
    int n = base + t * 4 + u;
    float wsum = 1.0f + (float)(hv[u] & ((1ull << 40) - 1)) * 9.5367431640625e-07f;
    dinv[n] = rsqrtf(wsum);
  }
  if (g == 0 && t == 0) rstart[NN] = NE;
}

// Split+transpose W1 [256k][512c] fp32 -> w1hi/w1lo [512c][256k] bf16 (k-contiguous)
__global__ __launch_bounds__(256) void k_w1t(const float* __restrict__ W1,
    unsigned short* __restrict__ hi, unsigned short* __restrict__ lo) {
  __shared__ unsigned short sh[64][72], sl[64][72];
  int bk = blockIdx.x & 3, bc = blockIdx.x >> 2;
  int k0 = bk * 64, c0 = bc * 64;
  int t = threadIdx.x;
#pragma unroll
  for (int s = 0; s < 16; ++s) {
    int i = t + s * 256;
    int k = i >> 6, c = i & 63;
    float v = W1[(k0 + k) * 512 + c0 + c];
    unsigned short h = bf16rne(v);
    float hf = __uint_as_float((unsigned)h << 16);
    sh[c][k] = h;
    sl[c][k] = bf16rne(v - hf);
  }
  __syncthreads();
#pragma unroll
  for (int s = 0; s < 16; ++s) {
    int i = t + s * 256;
    int c = i >> 6, k = i & 63;
    hi[(c0 + c) * 256 + k0 + k] = sh[c][k];
    lo[(c0 + c) * 256 + k0 + k] = sl[c][k];
  }
}

// Scatter edges to dest-sorted CSR: csr[pos] = coef<<32 | dest_local<<16 | src_local
__global__ void k_scatter(const int* __restrict__ ei, const float* __restrict__ w,
                          const float* __restrict__ dinv, unsigned* __restrict__ cursor,
                          unsigned long long* __restrict__ csr) {
  int e = blockIdx.x * 256 + threadIdx.x;
  if (e < NE) {
    int r = ei[e], c = ei[NE + e];
    float cf = w[e] * dinv[r] * dinv[c];
    unsigned pos = atomicAdd(&cursor[c], 1u);
    csr[pos] = ((unsigned long long)__float_as_uint(cf) << 32) |
               ((unsigned)(c & 1023) << 16) | (unsigned)(r & 1023);
  }
}

// Aggregate x over normalized adjacency -> y bf16 hi/lo planes.
// Block = (graph g, 16-col chunk), 1024 THREADS, ~140 KB LDS (1 block/CU,
// 16 waves/CU = 4 waves/SIMD -- doubles R12's wave count to cover the
// ds_read->fma stall). Whole-graph CSR staged in LDS (zero global loads in
// the inner loop); 64 groups x 16 lanes; each group owns 16 dests, pairs
// (d, d+8), batch-4 predicated.
__global__ __launch_bounds__(1024, 1) void k_aggx(const float* __restrict__ x,
    const unsigned long long* __restrict__ csr, const unsigned* __restrict__ rstart,
    const float* __restrict__ dinv, unsigned short* __restrict__ yhi,
    unsigned short* __restrict__ ylo, int gbase) {
  __shared__ float xs[1024 * 17];          // 68 KB
  __shared__ unsigned long long es[8192];  // 64 KB: whole graph's CSR
  __shared__ unsigned rp[1025];            // local (0..8192) segment starts
  __shared__ float dv2[1024];
  int bid = blockIdx.x;
  int g  = bid & 31;                // graph g -> XCD g%8 (L2 locality)
  int cc = bid >> 5;                // 16 chunks of 16 columns
  int gg = gbase + g;
  int c0 = cc * 16;
  int t = threadIdx.x;              // 0..1023
  int nbase = gg << 10;
  unsigned ebase = (unsigned)gg << 13;
  {
    int i = t;
    if (i < 1024) {
      rp[i] = rstart[nbase + i] - ebase;
      float dv = dinv[nbase + i];
      dv2[i] = dv * dv;
    }
  }
  if (t == 0) rp[1024] = 8192u;
  // stage whole-graph CSR: 8192 u64 = 4096 x 16B, 4 per thread
  {
    const u64x2* src = (const u64x2*)(csr + ebase);
    u64x2* dst = (u64x2*)es;
#pragma unroll
    for (int i = 0; i < 4; ++i)
      dst[t + i * 1024] = src[t + i * 1024];
  }
  // stage x[:, c0:c0+16] via float4 loads (4096 slots / 1024 threads)
#pragma unroll
  for (int s = 0; s < 4; ++s) {
    int i = t + s * 1024;           // float4-slot: row = i>>2, quad = i&3
    int row = i >> 2, q = (i & 3) * 4;
    float4 v = *(const float4*)&x[(nbase + row) * 256 + c0 + q];
    float* d = &xs[row * 17 + q];
    d[0] = v.x; d[1] = v.y; d[2] = v.z; d[3] = v.w;
  }
  __syncthreads();
  int j = t & 15, grp = t >> 4;     // 64 groups of 16 lanes; lane j = column
  int dbase = grp * 16;             // group owns dests [dbase, dbase+16)
  for (int dd = 0; dd < 8; ++dd) {
    int d0 = dbase + dd, d1 = d0 + 8;
    unsigned p0 = rp[d0], q0 = rp[d0 + 1];
    unsigned p1 = rp[d1], q1 = rp[d1 + 1];
    int L0 = (int)(q0 - p0), L1 = (int)(q1 - p1);
    int L = L0 > L1 ? L0 : L1;
    int M0 = L0 > 0 ? L0 - 1 : 0;   // clamp limits
    int M1 = L1 > 0 ? L1 - 1 : 0;
    float a0 = dv2[d0] * xs[d0 * 17 + j];
    float a1 = dv2[d1] * xs[d1 * 17 + j];
    for (int k = 0; k < L; k += 4) {
      unsigned long long cv0[4], cv1[4];
#pragma unroll
      for (int u = 0; u < 4; ++u) {
        int kk = k + u;
        int i0 = kk < M0 ? kk : M0;
        int i1 = kk < M1 ? kk : M1;
        cv0[u] = es[p0 + i0];
        cv1[u] = es[p1 + i1];
      }
#pragma unroll
      for (int u = 0; u < 4; ++u) {
        int kk = k + u;
        float f0 = kk < L0 ? __uint_as_float((unsigned)(cv0[u] >> 32)) : 0.0f;
        float f1 = kk < L1 ? __uint_as_float((unsigned)(cv1[u] >> 32)) : 0.0f;
        a0 += f0 * xs[(unsigned)(cv0[u] & 1023) * 17 + j];
        a1 += f1 * xs[(unsigned)(cv1[u] & 1023) * 17 + j];
      }
    }
    int i0 = ((g << 10) + d0) * 256 + c0 + j;
    int i1 = ((g << 10) + d1) * 256 + c0 + j;
    unsigned short h0 = bf16rne(a0), h1 = bf16rne(a1);
    yhi[i0] = h0;
    ylo[i0] = bf16rne(a0 - __uint_as_float((unsigned)h0 << 16));
    yhi[i1] = h1;
    ylo[i1] = bf16rne(a1 - __uint_as_float((unsigned)h1 << 16));
  }
}

// MFMA GEMM: h = y(32768x256) @ W1(256x512) via bf16 hi/lo 3-product split,
// fused +b1 -> LeakyReLU -> dot W2 -> atomic z.  128x128 tile, 4 waves (64x64).
__global__ __launch_bounds__(256, 2) void k_gemm(
    const unsigned short* __restrict__ yhi, const unsigned short* __restrict__ ylo,
    const unsigned short* __restrict__ w1hi, const unsigned short* __restrict__ w1lo,
    const float* __restrict__ b1, const float* __restrict__ W2,
    float* __restrict__ z, int node_base) {
  __shared__ unsigned short Ah_s[128 * 40], Al_s[128 * 40];  // [row][40] ushort, 80B stride
  __shared__ unsigned short Bh_s[128 * 40], Bl_s[128 * 40];  // [col][40]
  int bx = blockIdx.x & 3, by = blockIdx.x >> 2;
  int r0 = by * 128, c0 = bx * 128;
  int t = threadIdx.x;
  int lane = t & 63, wid = t >> 6;
  int wr = wid >> 1, wc = wid & 1;         // wave tile origin (wr*64, wc*64)
  int lr = lane & 15, hg = lane >> 4;
  f32x4 acc[4][4];
#pragma unroll
  for (int m = 0; m < 4; ++m)
#pragma unroll
    for (int n = 0; n < 4; ++n)
      acc[m][n] = (f32x4){0.0f, 0.0f, 0.0f, 0.0f};
  int rr = t >> 2, kq = (t & 3) * 8;       // staging: rows rr, rr+64; 8-elem k-chunk
  for (int kt = 0; kt < 256; kt += 32) {
    us8 va0 = *(const us8*)&yhi[(r0 + rr) * 256 + kt + kq];
    us8 va1 = *(const us8*)&yhi[(r0 + rr + 64) * 256 + kt + kq];
    us8 vb0 = *(const us8*)&ylo[(r0 + rr) * 256 + kt + kq];
    us8 vb1 = *(const us8*)&ylo[(r0 + rr + 64) * 256 + kt + kq];
    us8 vc0 = *(const us8*)&w1hi[(c0 + rr) * 256 + kt + kq];
    us8 vc1 = *(const us8*)&w1hi[(c0 + rr + 64) * 256 + kt + kq];
    us8 vd0 = *(const us8*)&w1lo[(c0 + rr) * 256 + kt + kq];
    us8 vd1 = *(const us8*)&w1lo[(c0 + rr + 64) * 256 + kt + kq];
    __syncthreads();                        // prev-step frag reads complete
    *(us8*)&Ah_s[rr * 40 + kq] = va0;  *(us8*)&Ah_s[(rr + 64) * 40 + kq] = va1;
    *(us8*)&Al_s[rr * 40 + kq] = vb0;  *(us8*)&Al_s[(rr + 64) * 40 + kq] = vb1;
    *(us8*)&Bh_s[rr * 40 + kq] = vc0;  *(us8*)&Bh_s[(rr + 64) * 40 + kq] = vc1;
    *(us8*)&Bl_s[rr * 40 + kq] = vd0;  *(us8*)&Bl_s[(rr + 64) * 40 + kq] = vd1;
    __syncthreads();
    bfrag Ah[4], Al[4], Bh[4], Bl[4];
#pragma unroll
    for (int m = 0; m < 4; ++m) {
      int ra = (wr * 64 + m * 16 + lr) * 40 + hg * 8;
      Ah[m] = *(const bfrag*)&Ah_s[ra];
      Al[m] = *(const bfrag*)&Al_s[ra];
      int rb = (wc * 64 + m * 16 + lr) * 40 + hg * 8;
      Bh[m] = *(const bfrag*)&Bh_s[rb];
      Bl[m] = *(const bfrag*)&Bl_s[rb];
    }
#pragma unroll
    for (int m = 0; m < 4; ++m)
#pragma unroll
      for (int n = 0; n < 4; ++n) {
        acc[m][n] = __builtin_amdgcn_mfma_f32_16x16x32_bf16(Ah[m], Bh[n], acc[m][n], 0, 0, 0);
        acc[m][n] = __builtin_amdgcn_mfma_f32_16x16x32_bf16(Ah[m], Bl[n], acc[m][n], 0, 0, 0);
        acc[m][n] = __builtin_amdgcn_mfma_f32_16x16x32_bf16(Al[m], Bh[n], acc[m][n], 0, 0, 0);
      }
  }
  // epilogue: +b1, LeakyReLU, dot W2, reduce over the 16 col-lanes, atomic z
  float p[4][4];
#pragma unroll
  for (int m = 0; m < 4; ++m)
#pragma unroll
    for (int i = 0; i < 4; ++i) p[m][i] = 0.0f;
#pragma unroll
  for (int n = 0; n < 4; ++n) {
    int col = c0 + wc * 64 + n * 16 + lr;
    float b1v = b1[col], w2v = W2[col];
#pragma unroll
    for (int m = 0; m < 4; ++m)
#pragma unroll
      for (int i = 0; i < 4; ++i) {
        float v = acc[m][n][i] + b1v;
        v = v > 0.0f ? v : 0.01f * v;
        p[m][i] += v * w2v;
      }
  }
#pragma unroll
  for (int off = 8; off > 0; off >>= 1)
#pragma unroll
    for (int m = 0; m < 4; ++m)
#pragma unroll
      for (int i = 0; i < 4; ++i)
        p[m][i] += __shfl_xor(p[m][i], off, 16);
  if (lr == 0) {
    int rbase = node_base + r0 + wr * 64 + hg * 4;
#pragma unroll
    for (int m = 0; m < 4; ++m)
#pragma unroll
      for (int i = 0; i < 4; ++i)
        unsafeAtomicAdd(&z[rbase + m * 16 + i], p[m][i]);
  }
}

// score[n] = b2 + dinv[n]^2*z[n] + sum_{e in seg(n)} coef[e]*z[global_row]
// Also initializes mask[n] = -1 (fused, saves a launch).
__global__ void k_score(const unsigned long long* __restrict__ csr,
                        const unsigned* __restrict__ rstart,
                        const float* __restrict__ dinv, const float* __restrict__ z,
                        const float* __restrict__ b2, float* __restrict__ score,
                        int* __restrict__ mask) {
  int n = blockIdx.x * 256 + threadIdx.x;
  if (n >= NN) return;
  mask[n] = -1;
  int nb = n & ~1023;
  float dv = dinv[n];
  float a = b2[0] + dv * dv * z[n];
  unsigned s = rstart[n], epos = rstart[n + 1];
  for (unsigned e = s; e < epos; ++e) {
    unsigned long long p = csr[e];
    a += __uint_as_float((unsigned)(p >> 32)) * z[nb + (unsigned)(p & 1023)];
  }
  score[n] = a;
}

__device__ void bitonic(unsigned long long* keys, int n, int t, int nt) {
  for (int k = 2; k <= n; k <<= 1)
    for (int jj = k >> 1; jj > 0; jj >>= 1) {
      __syncthreads();
      for (int i = t; i < n; i += nt) {
        int ixj = i ^ jj;
        if (ixj > i) {
          unsigned long long a = keys[i], c = keys[ixj];
          bool up = ((i & k) == 0);
          if ((a > c) == up) { keys[i] = c; keys[ixj] = a; }
        }
      }
    }
  __syncthreads();
}

__global__ __launch_bounds__(256) void k_topk(const float* __restrict__ score,
                                              int* __restrict__ mask,
                                              float* __restrict__ out) {
  __shared__ unsigned long long keys[1024];
  int b = blockIdx.x, t = threadIdx.x;
  int base = b << 10;
  if (t < 64) {
    float v = score[base + t];
    keys[t] = ((unsigned long long)(~monof(v)) << 32) | (unsigned)t;
    out[O6 + b * 64 + t] = v;
    out[O7 + b * 64 + t] = (float)b;
  }
  __syncthreads();
  bitonic(keys, 64, t, 256);
  if (t < 3) {
    int idx = (int)(keys[t] & 0xFFFFFFFFull);
    int node = base + idx;
    int pos = b * 3 + t;
    mask[node] = pos;
    out[O4 + pos] = (float)node;
    out[O5 + pos] = score[node];
    out[O3 + pos] = (float)b;
  }
  __syncthreads();
  for (int i = t; i < 1024; i += 256) {
    if (i < 960) {
      float v = score[base + 64 + i];
      keys[i] = ((unsigned long long)(~monof(v)) << 32) | (unsigned)i;
    } else {
      keys[i] = 0xFFFFFFFFFFFFFFFFull;
    }
  }
  __syncthreads();
  bitonic(keys, 1024, t, 256);
  for (int r = t; r < 480; r += 256) {
    int idx = (int)(keys[r] & 0xFFFFFFFFull);
    int node = base + 64 + idx;
    int pos = 192 + b * 480 + r;
    mask[node] = pos;
    out[O4 + pos] = (float)node;
    out[O5 + pos] = score[node];
    out[O3 + pos] = (float)b;
  }
}

__global__ void k_edges(const int* __restrict__ ei, const float* __restrict__ w,
                        const int* __restrict__ mask, float* __restrict__ out) {
  int e = blockIdx.x * 256 + threadIdx.x;
  if (e >= NE) return;
  int nr = mask[ei[e]];
  int nc = mask[ei[NE + e]];
  bool keep = (nr >= 0) && (nc >= 0);
  out[O1 + e]      = keep ? (float)nr : -1.0f;
  out[O1 + NE + e] = keep ? (float)nc : -1.0f;
  out[O2 + e]      = keep ? w[e] : 0.0f;
  out[O8 + e]      = keep ? 1.0f : 0.0f;
}

__global__ void k_xout(const float* __restrict__ x, const float* __restrict__ permF,
                       const float* __restrict__ scoreP, float* __restrict__ out) {
  int i = blockIdx.x;
  int node = (int)permF[i];
  float s = scoreP[i];
  const float4* xr = (const float4*)&x[node * 256];
  float4* o = (float4*)&out[i * 256];
  float4 v = xr[threadIdx.x];
  o[threadIdx.x] = make_float4(v.x * s, v.y * s, v.z * s, v.w * s);
}

extern "C" void kernel_launch(void* const* d_in, const int* in_sizes, int n_in,
                              void* d_out, int out_size, void* d_ws, size_t ws_size,
                              hipStream_t stream) {
  (void)in_sizes; (void)n_in; (void)out_size; (void)d_ws; (void)ws_size;
  const float* x  = (const float*)d_in[0];
  const int*   ei = (const int*)d_in[1];
  const float* w  = (const float*)d_in[2];
  const float* W1 = (const float*)d_in[4];
  const float* b1 = (const float*)d_in[5];
  const float* W2 = (const float*)d_in[6];
  const float* b2 = (const float*)d_in[7];
  float* out    = (float*)d_out;
  unsigned short* yhi = (unsigned short*)out;                  // [32768*256] per chunk
  unsigned short* ylo = (unsigned short*)(out + YLO_OFF);
  unsigned long long* csr = (unsigned long long*)(out + CSR_OFF);
  float* dinv   = out + DINV_OFF;
  float* z      = out + Z_OFF;
  unsigned* rstart = (unsigned*)(out + RSTART_OFF);
  unsigned* cursor = (unsigned*)(out + CURSOR_OFF);
  unsigned long long* hist64 = (unsigned long long*)(out + HIST_OFF);
  unsigned short* w1hi = (unsigned short*)(out + W1HI_OFF);
  unsigned short* w1lo = (unsigned short*)(out + W1LO_OFF);
  float* score  = out + SCORE_OFF;
  int*   mask   = (int*)d_out;

  k_zero<<<256, 256, 0, stream>>>(hist64, z);
  k_hist<<<2048, 256, 0, stream>>>(ei, w, hist64);
  k_prefix<<<64, 256, 0, stream>>>(hist64, rstart, cursor, dinv);
  k_w1t<<<32, 256, 0, stream>>>(W1, w1hi, w1lo);
  k_scatter<<<2048, 256, 0, stream>>>(ei, w, dinv, cursor, csr);
  for (int ch = 0; ch < 2; ++ch) {
    k_aggx<<<512, 1024, 0, stream>>>(x, csr, rstart, dinv, yhi, ylo, ch * 32);
    k_gemm<<<1024, 256, 0, stream>>>(yhi, ylo, w1hi, w1lo, b1, W2, z, ch * 32768);
  }
  k_score<<<256, 256, 0, stream>>>(csr, rstart, dinv, z, b2, score, mask);
  k_topk<<<64, 256, 0, stream>>>(score, mask, out);
  k_edges<<<2048, 256, 0, stream>>>(ei, w, mask, out);
  k_xout<<<30912, 64, 0, stream>>>(x, out + O4, out + O5, out);
}

// Round 14
// 251.240 us; speedup vs baseline: 1.5304x; 1.0327x over previous
//
#include <hip/hip_runtime.h>

// Problem constants
#define NN   65536      // N nodes
#define NE   524288     // E edges
#define EPG  8192       // edges per graph

// Output float offsets in d_out (total 10111552 floats)
#define O1 7913472      // ei_new (2*E)
#define O2 8962048      // ea_new (E)
#define O3 9486336      // batch_out (30912)
#define O4 9517248      // perm (30912)
#define O5 9548160      // score_perm (30912)
#define O6 9579072      // sentence_scores (4096)
#define O7 9583168      // sentence_batch (4096)
#define O8 9587264      // keep (E)

// Scratch placement (float offsets), lifetime-verified (same as R9-R13):
#define CSR_OFF    8388608
#define DINV_OFF   9437184
#define Z_OFF      9502720
#define W1HI_OFF   9568256
#define RSTART_OFF 9633792
#define CURSOR_OFF 9699344
#define W1LO_OFF   9764880
#define HIST_OFF   9830416
#define SCORE_OFF  65536
#define YLO_OFF    4194304   // ushort-plane offsets: yhi at float 0, ylo at float 4194304

typedef __attribute__((ext_vector_type(8))) short bfrag;
typedef __attribute__((ext_vector_type(4))) float f32x4;
typedef __attribute__((ext_vector_type(8))) unsigned short us8;
typedef __attribute__((ext_vector_type(2))) unsigned long long u64x2;

__device__ __forceinline__ unsigned monof(float f) {
  unsigned u = __float_as_uint(f);
  return (u & 0x80000000u) ? ~u : (u | 0x80000000u);  // ascending monotone map
}

__device__ __forceinline__ unsigned short bf16rne(float f) {
  unsigned u = __float_as_uint(f);
  return (unsigned short)((u + 0x7FFFu + ((u >> 16) & 1u)) >> 16);
}

__global__ void k_zero(unsigned long long* __restrict__ hist, float* __restrict__ z) {
  int n = blockIdx.x * 256 + threadIdx.x;
  if (n < NN) { hist[n] = 0ull; z[n] = 0.0f; }
}

// One packed u64 atomic per edge: count in bits>=40, wsum fixed-point 2^-20 below.
__global__ void k_hist(const int* __restrict__ ei, const float* __restrict__ w,
                       unsigned long long* __restrict__ hist) {
  int e = blockIdx.x * 256 + threadIdx.x;
  if (e < NE) {
    int c = ei[NE + e];
    unsigned long long add = (1ull << 40) |
        (unsigned long long)(unsigned)__float2uint_rn(w[e] * 1048576.0f);
    atomicAdd(&hist[c], add);
  }
}

// Per graph: exclusive prefix over 1024 bins -> rstart/cursor; dinv from fixed-point wsum.
__global__ __launch_bounds__(256) void k_prefix(const unsigned long long* __restrict__ hist,
    unsigned* __restrict__ rstart, unsigned* __restrict__ cursor, float* __restrict__ dinv) {
  __shared__ unsigned tmp[2][256];
  int g = blockIdx.x, t = threadIdx.x;
  int base = g << 10;
  unsigned c[4], sum = 0;
  unsigned long long hv[4];
#pragma unroll
  for (int u = 0; u < 4; ++u) {
    hv[u] = hist[base + t * 4 + u];
    c[u] = (unsigned)(hv[u] >> 40);
    sum += c[u];
  }
  tmp[0][t] = sum;
  __syncthreads();
  int pin = 0;
  for (int off = 1; off < 256; off <<= 1) {
    int pout = pin ^ 1;
    unsigned v = tmp[pin][t];
    if (t >= off) v += tmp[pin][t - off];
    tmp[pout][t] = v;
    __syncthreads();
    pin = pout;
  }
  unsigned run = (t == 0) ? 0u : tmp[pin][t - 1];
#pragma unroll
  for (int u = 0; u < 4; ++u) {
    unsigned pos = (unsigned)(g << 13) + run;   // g*8192 + prefix
    rstart[base + t * 4 + u] = pos;
    cursor[base + t * 4 + u] = pos;
    run += c[u];
  }
#pragma unroll
  for (int u = 0; u < 4; ++u) {
    int n = base + t * 4 + u;
    float wsum = 1.0f + (float)(hv[u] & ((1ull << 40) - 1)) * 9.5367431640625e-07f;
    dinv[n] = rsqrtf(wsum);
  }
  if (g == 0 && t == 0) rstart[NN] = NE;
}

// Split+transpose W1 [256k][512c] fp32 -> w1hi/w1lo [512c][256k] bf16 (k-contiguous)
__global__ __launch_bounds__(256) void k_w1t(const float* __restrict__ W1,
    unsigned short* __restrict__ hi, unsigned short* __restrict__ lo) {
  __shared__ unsigned short sh[64][72], sl[64][72];
  int bk = blockIdx.x & 3, bc = blockIdx.x >> 2;
  int k0 = bk * 64, c0 = bc * 64;
  int t = threadIdx.x;
#pragma unroll
  for (int s = 0; s < 16; ++s) {
    int i = t + s * 256;
    int k = i >> 6, c = i & 63;
    float v = W1[(k0 + k) * 512 + c0 + c];
    unsigned short h = bf16rne(v);
    float hf = __uint_as_float((unsigned)h << 16);
    sh[c][k] = h;
    sl[c][k] = bf16rne(v - hf);
  }
  __syncthreads();
#pragma unroll
  for (int s = 0; s < 16; ++s) {
    int i = t + s * 256;
    int c = i >> 6, k = i & 63;
    hi[(c0 + c) * 256 + k0 + k] = sh[c][k];
    lo[(c0 + c) * 256 + k0 + k] = sl[c][k];
  }
}

// Scatter edges to dest-sorted CSR:
// entry = coef<<32 | src_local<<15 | src_local*18   (pre-scaled LDS row offset)
__global__ void k_scatter(const int* __restrict__ ei, const float* __restrict__ w,
                          const float* __restrict__ dinv, unsigned* __restrict__ cursor,
                          unsigned long long* __restrict__ csr) {
  int e = blockIdx.x * 256 + threadIdx.x;
  if (e < NE) {
    int r = ei[e], c = ei[NE + e];
    float cf = w[e] * dinv[r] * dinv[c];
    unsigned pos = atomicAdd(&cursor[c], 1u);
    unsigned sl = (unsigned)(r & 1023);
    csr[pos] = ((unsigned long long)__float_as_uint(cf) << 32) |
               (sl << 15) | (sl * 18u);
  }
}

// Aggregate x over normalized adjacency -> y bf16 hi/lo planes.
// Block = (graph g, 16-col chunk), 1024 threads, ~144 KB LDS, whole-graph CSR
// in LDS. NEW: 8 lanes per edge, 2 columns per lane (float2 xs reads, b64),
// halving VALU+LDS instructions per edge-visit; sentinel entry es[8192]=0
// replaces result predication (out-of-segment reads fma 0). 64 groups of
// 16 lanes; group owns 16 dests; halves process pair (d, d+8) batch-4.
__global__ __launch_bounds__(1024, 1) void k_aggx(const float* __restrict__ x,
    const unsigned long long* __restrict__ csr, const unsigned* __restrict__ rstart,
    const float* __restrict__ dinv, unsigned short* __restrict__ yhi,
    unsigned short* __restrict__ ylo, int gbase) {
  __shared__ float xs[1024 * 18];          // 72 KB, stride-18 rows (float2-aligned)
  __shared__ unsigned long long es[8193];  // 64 KB CSR + zero sentinel
  __shared__ unsigned rp[1025];            // local segment starts
  __shared__ float dv2[1024];
  int bid = blockIdx.x;
  int g  = bid & 31;                // graph g -> XCD g%8 (L2 locality)
  int cc = bid >> 5;                // 16 chunks of 16 columns
  int gg = gbase + g;
  int c0 = cc * 16;
  int t = threadIdx.x;              // 0..1023
  int nbase = gg << 10;
  unsigned ebase = (unsigned)gg << 13;
  {
    rp[t] = rstart[nbase + t] - ebase;
    float dv = dinv[nbase + t];
    dv2[t] = dv * dv;
  }
  if (t == 0) { rp[1024] = 8192u; es[8192] = 0ull; }
  // stage whole-graph CSR: 4096 x 16B, 4 per thread
  {
    const u64x2* src = (const u64x2*)(csr + ebase);
    u64x2* dst = (u64x2*)es;
#pragma unroll
    for (int i = 0; i < 4; ++i)
      dst[t + i * 1024] = src[t + i * 1024];
  }
  // stage x[:, c0:c0+16]: float4 global loads, two float2 LDS writes each
#pragma unroll
  for (int s = 0; s < 4; ++s) {
    int i = t + s * 1024;           // float4-slot: row = i>>2, quad = i&3
    int row = i >> 2, q = (i & 3) * 4;
    float4 v = *(const float4*)&x[(nbase + row) * 256 + c0 + q];
    float* d = &xs[row * 18 + q];
    *(float2*)&d[0] = make_float2(v.x, v.y);
    *(float2*)&d[2] = make_float2(v.z, v.w);
  }
  __syncthreads();
  int jj = t & 7;                   // 2-col lane: cols c0+2jj, c0+2jj+1
  int h  = (t >> 3) & 1;            // half: segment d0 (h=0) or d1 (h=1)
  int grp = t >> 4;                 // 64 groups of 16 lanes
  int dbase = grp * 16;             // group owns dests [dbase, dbase+16)
  int j2 = 2 * jj;
  for (int dd = 0; dd < 8; ++dd) {
    int d0 = dbase + dd;
    unsigned pA = rp[d0], qA = rp[d0 + 1];
    unsigned pB = rp[d0 + 8], qB = rp[d0 + 9];
    int L0 = (int)(qA - pA), L1 = (int)(qB - pB);
    int L = L0 > L1 ? L0 : L1;      // group-uniform trip count
    int d = d0 + 8 * h;             // this half's dest
    unsigned p = h ? pB : pA;
    unsigned q = h ? qB : qA;
    float2 xv = *(const float2*)&xs[d * 18 + j2];
    float dv = dv2[d];
    float ax = dv * xv.x, ay = dv * xv.y;
    for (int k = 0; k < L; k += 4) {
      unsigned long long cv[4];
#pragma unroll
      for (int u = 0; u < 4; ++u) {
        unsigned a = p + (unsigned)(k + u);
        cv[u] = es[a < q ? a : 8192u];   // sentinel: coef 0
      }
#pragma unroll
      for (int u = 0; u < 4; ++u) {
        float cf = __uint_as_float((unsigned)(cv[u] >> 32));
        const float2 xr = *(const float2*)&xs[((unsigned)cv[u] & 0x7FFFu) + j2];
        ax += cf * xr.x;
        ay += cf * xr.y;
      }
    }
    int idx = ((g << 10) + d) * 256 + c0 + j2;
    unsigned short hx = bf16rne(ax), hy = bf16rne(ay);
    float lx = ax - __uint_as_float((unsigned)hx << 16);
    float ly = ay - __uint_as_float((unsigned)hy << 16);
    *(unsigned*)&yhi[idx] = (unsigned)hx | ((unsigned)hy << 16);
    *(unsigned*)&ylo[idx] = (unsigned)bf16rne(lx) | ((unsigned)bf16rne(ly) << 16);
  }
}

// MFMA GEMM: h = y(32768x256) @ W1(256x512) via bf16 hi/lo 3-product split,
// fused +b1 -> LeakyReLU -> dot W2 -> atomic z.  128x128 tile, 4 waves (64x64).
__global__ __launch_bounds__(256, 2) void k_gemm(
    const unsigned short* __restrict__ yhi, const unsigned short* __restrict__ ylo,
    const unsigned short* __restrict__ w1hi, const unsigned short* __restrict__ w1lo,
    const float* __restrict__ b1, const float* __restrict__ W2,
    float* __restrict__ z, int node_base) {
  __shared__ unsigned short Ah_s[128 * 40], Al_s[128 * 40];  // [row][40] ushort, 80B stride
  __shared__ unsigned short Bh_s[128 * 40], Bl_s[128 * 40];  // [col][40]
  int bx = blockIdx.x & 3, by = blockIdx.x >> 2;
  int r0 = by * 128, c0 = bx * 128;
  int t = threadIdx.x;
  int lane = t & 63, wid = t >> 6;
  int wr = wid >> 1, wc = wid & 1;         // wave tile origin (wr*64, wc*64)
  int lr = lane & 15, hg = lane >> 4;
  f32x4 acc[4][4];
#pragma unroll
  for (int m = 0; m < 4; ++m)
#pragma unroll
    for (int n = 0; n < 4; ++n)
      acc[m][n] = (f32x4){0.0f, 0.0f, 0.0f, 0.0f};
  int rr = t >> 2, kq = (t & 3) * 8;       // staging: rows rr, rr+64; 8-elem k-chunk
  for (int kt = 0; kt < 256; kt += 32) {
    us8 va0 = *(const us8*)&yhi[(r0 + rr) * 256 + kt + kq];
    us8 va1 = *(const us8*)&yhi[(r0 + rr + 64) * 256 + kt + kq];
    us8 vb0 = *(const us8*)&ylo[(r0 + rr) * 256 + kt + kq];
    us8 vb1 = *(const us8*)&ylo[(r0 + rr + 64) * 256 + kt + kq];
    us8 vc0 = *(const us8*)&w1hi[(c0 + rr) * 256 + kt + kq];
    us8 vc1 = *(const us8*)&w1hi[(c0 + rr + 64) * 256 + kt + kq];
    us8 vd0 = *(const us8*)&w1lo[(c0 + rr) * 256 + kt + kq];
    us8 vd1 = *(const us8*)&w1lo[(c0 + rr + 64) * 256 + kt + kq];
    __syncthreads();                        // prev-step frag reads complete
    *(us8*)&Ah_s[rr * 40 + kq] = va0;  *(us8*)&Ah_s[(rr + 64) * 40 + kq] = va1;
    *(us8*)&Al_s[rr * 40 + kq] = vb0;  *(us8*)&Al_s[(rr + 64) * 40 + kq] = vb1;
    *(us8*)&Bh_s[rr * 40 + kq] = vc0;  *(us8*)&Bh_s[(rr + 64) * 40 + kq] = vc1;
    *(us8*)&Bl_s[rr * 40 + kq] = vd0;  *(us8*)&Bl_s[(rr + 64) * 40 + kq] = vd1;
    __syncthreads();
    bfrag Ah[4], Al[4], Bh[4], Bl[4];
#pragma unroll
    for (int m = 0; m < 4; ++m) {
      int ra = (wr * 64 + m * 16 + lr) * 40 + hg * 8;
      Ah[m] = *(const bfrag*)&Ah_s[ra];
      Al[m] = *(const bfrag*)&Al_s[ra];
      int rb = (wc * 64 + m * 16 + lr) * 40 + hg * 8;
      Bh[m] = *(const bfrag*)&Bh_s[rb];
      Bl[m] = *(const bfrag*)&Bl_s[rb];
    }
#pragma unroll
    for (int m = 0; m < 4; ++m)
#pragma unroll
      for (int n = 0; n < 4; ++n) {
        acc[m][n] = __builtin_amdgcn_mfma_f32_16x16x32_bf16(Ah[m], Bh[n], acc[m][n], 0, 0, 0);
        acc[m][n] = __builtin_amdgcn_mfma_f32_16x16x32_bf16(Ah[m], Bl[n], acc[m][n], 0, 0, 0);
        acc[m][n] = __builtin_amdgcn_mfma_f32_16x16x32_bf16(Al[m], Bh[n], acc[m][n], 0, 0, 0);
      }
  }
  // epilogue: +b1, LeakyReLU, dot W2, reduce over the 16 col-lanes, atomic z
  float p[4][4];
#pragma unroll
  for (int m = 0; m < 4; ++m)
#pragma unroll
    for (int i = 0; i < 4; ++i) p[m][i] = 0.0f;
#pragma unroll
  for (int n = 0; n < 4; ++n) {
    int col = c0 + wc * 64 + n * 16 + lr;
    float b1v = b1[col], w2v = W2[col];
#pragma unroll
    for (int m = 0; m < 4; ++m)
#pragma unroll
      for (int i = 0; i < 4; ++i) {
        float v = acc[m][n][i] + b1v;
        v = v > 0.0f ? v : 0.01f * v;
        p[m][i] += v * w2v;
      }
  }
#pragma unroll
  for (int off = 8; off > 0; off >>= 1)
#pragma unroll
    for (int m = 0; m < 4; ++m)
#pragma unroll
      for (int i = 0; i < 4; ++i)
        p[m][i] += __shfl_xor(p[m][i], off, 16);
  if (lr == 0) {
    int rbase = node_base + r0 + wr * 64 + hg * 4;
#pragma unroll
    for (int m = 0; m < 4; ++m)
#pragma unroll
      for (int i = 0; i < 4; ++i)
        unsafeAtomicAdd(&z[rbase + m * 16 + i], p[m][i]);
  }
}

// score[n] = b2 + dinv[n]^2*z[n] + sum_{e in seg(n)} coef[e]*z[global_row]
// src is entry bits 15-24. Also initializes mask[n] = -1 (fused).
__global__ void k_score(const unsigned long long* __restrict__ csr,
                        const unsigned* __restrict__ rstart,
                        const float* __restrict__ dinv, const float* __restrict__ z,
                        const float* __restrict__ b2, float* __restrict__ score,
                        int* __restrict__ mask) {
  int n = blockIdx.x * 256 + threadIdx.x;
  if (n >= NN) return;
  mask[n] = -1;
  int nb = n & ~1023;
  float dv = dinv[n];
  float a = b2[0] + dv * dv * z[n];
  unsigned s = rstart[n], epos = rstart[n + 1];
  for (unsigned e = s; e < epos; ++e) {
    unsigned long long p = csr[e];
    a += __uint_as_float((unsigned)(p >> 32)) * z[nb + (((unsigned)p >> 15) & 1023u)];
  }
  score[n] = a;
}

__device__ void bitonic(unsigned long long* keys, int n, int t, int nt) {
  for (int k = 2; k <= n; k <<= 1)
    for (int jj = k >> 1; jj > 0; jj >>= 1) {
      __syncthreads();
      for (int i = t; i < n; i += nt) {
        int ixj = i ^ jj;
        if (ixj > i) {
          unsigned long long a = keys[i], c = keys[ixj];
          bool up = ((i & k) == 0);
          if ((a > c) == up) { keys[i] = c; keys[ixj] = a; }
        }
      }
    }
  __syncthreads();
}

__global__ __launch_bounds__(256) void k_topk(const float* __restrict__ score,
                                              int* __restrict__ mask,
                                              float* __restrict__ out) {
  __shared__ unsigned long long keys[1024];
  int b = blockIdx.x, t = threadIdx.x;
  int base = b << 10;
  if (t < 64) {
    float v = score[base + t];
    keys[t] = ((unsigned long long)(~monof(v)) << 32) | (unsigned)t;
    out[O6 + b * 64 + t] = v;
    out[O7 + b * 64 + t] = (float)b;
  }
  __syncthreads();
  bitonic(keys, 64, t, 256);
  if (t < 3) {
    int idx = (int)(keys[t] & 0xFFFFFFFFull);
    int node = base + idx;
    int pos = b * 3 + t;
    mask[node] = pos;
    out[O4 + pos] = (float)node;
    out[O5 + pos] = score[node];
    out[O3 + pos] = (float)b;
  }
  __syncthreads();
  for (int i = t; i < 1024; i += 256) {
    if (i < 960) {
      float v = score[base + 64 + i];
      keys[i] = ((unsigned long long)(~monof(v)) << 32) | (unsigned)i;
    } else {
      keys[i] = 0xFFFFFFFFFFFFFFFFull;
    }
  }
  __syncthreads();
  bitonic(keys, 1024, t, 256);
  for (int r = t; r < 480; r += 256) {
    int idx = (int)(keys[r] & 0xFFFFFFFFull);
    int node = base + 64 + idx;
    int pos = 192 + b * 480 + r;
    mask[node] = pos;
    out[O4 + pos] = (float)node;
    out[O5 + pos] = score[node];
    out[O3 + pos] = (float)b;
  }
}

__global__ void k_edges(const int* __restrict__ ei, const float* __restrict__ w,
                        const int* __restrict__ mask, float* __restrict__ out) {
  int e = blockIdx.x * 256 + threadIdx.x;
  if (e >= NE) return;
  int nr = mask[ei[e]];
  int nc = mask[ei[NE + e]];
  bool keep = (nr >= 0) && (nc >= 0);
  out[O1 + e]      = keep ? (float)nr : -1.0f;
  out[O1 + NE + e] = keep ? (float)nc : -1.0f;
  out[O2 + e]      = keep ? w[e] : 0.0f;
  out[O8 + e]      = keep ? 1.0f : 0.0f;
}

__global__ void k_xout(const float* __restrict__ x, const float* __restrict__ permF,
                       const float* __restrict__ scoreP, float* __restrict__ out) {
  int i = blockIdx.x;
  int node = (int)permF[i];
  float s = scoreP[i];
  const float4* xr = (const float4*)&x[node * 256];
  float4* o = (float4*)&out[i * 256];
  float4 v = xr[threadIdx.x];
  o[threadIdx.x] = make_float4(v.x * s, v.y * s, v.z * s, v.w * s);
}

extern "C" void kernel_launch(void* const* d_in, const int* in_sizes, int n_in,
                              void* d_out, int out_size, void* d_ws, size_t ws_size,
                              hipStream_t stream) {
  (void)in_sizes; (void)n_in; (void)out_size; (void)d_ws; (void)ws_size;
  const float* x  = (const float*)d_in[0];
  const int*   ei = (const int*)d_in[1];
  const float* w  = (const float*)d_in[2];
  const float* W1 = (const float*)d_in[4];
  const float* b1 = (const float*)d_in[5];
  const float* W2 = (const float*)d_in[6];
  const float* b2 = (const float*)d_in[7];
  float* out    = (float*)d_out;
  unsigned short* yhi = (unsigned short*)out;                  // [32768*256] per chunk
  unsigned short* ylo = (unsigned short*)(out + YLO_OFF);
  unsigned long long* csr = (unsigned long long*)(out + CSR_OFF);
  float* dinv   = out + DINV_OFF;
  float* z      = out + Z_OFF;
  unsigned* rstart = (unsigned*)(out + RSTART_OFF);
  unsigned* cursor = (unsigned*)(out + CURSOR_OFF);
  unsigned long long* hist64 = (unsigned long long*)(out + HIST_OFF);
  unsigned short* w1hi = (unsigned short*)(out + W1HI_OFF);
  unsigned short* w1lo = (unsigned short*)(out + W1LO_OFF);
  float* score  = out + SCORE_OFF;
  int*   mask   = (int*)d_out;

  k_zero<<<256, 256, 0, stream>>>(hist64, z);
  k_hist<<<2048, 256, 0, stream>>>(ei, w, hist64);
  k_prefix<<<64, 256, 0, stream>>>(hist64, rstart, cursor, dinv);
  k_w1t<<<32, 256, 0, stream>>>(W1, w1hi, w1lo);
  k_scatter<<<2048, 256, 0, stream>>>(ei, w, dinv, cursor, csr);
  for (int ch = 0; ch < 2; ++ch) {
    k_aggx<<<512, 1024, 0, stream>>>(x, csr, rstart, dinv, yhi, ylo, ch * 32);
    k_gemm<<<1024, 256, 0, stream>>>(yhi, ylo, w1hi, w1lo, b1, W2, z, ch * 32768);
  }
  k_score<<<256, 256, 0, stream>>>(csr, rstart, dinv, z, b2, score, mask);
  k_topk<<<64, 256, 0, stream>>>(score, mask, out);
  k_edges<<<2048, 256, 0, stream>>>(ei, w, mask, out);
  k_xout<<<30912, 64, 0, stream>>>(x, out + O4, out + O5, out);
}